// Round 16
// baseline (384.467 us; speedup 1.0000x reference)
//
#include <hip/hip_runtime.h>
#include <float.h>
#include <math.h>

#define BCLOUDS 16
#define PPTS    1024
#define NPTS    (BCLOUDS * PPTS)
#define KNB     32
#define NCLS    40
#define RPB     8                  // rows per knn block; wave w owns rows {w, w+4}
#define NBIN    256
#define HPADW   (NBIN + NBIN / 16)
#define SELFM   0xFFFFFFFFu        // self marker: above every real distance bit pattern

__device__ __forceinline__ int hidx(int b) { return b + (b >> 4); }

// ---------------------------------------------------------------------------
// Transpose + norms: xT[cloud][f][p] = x[cloud*1024+p][f]; qn[p] = |x_p|^2
// ---------------------------------------------------------------------------
template<int F>
__global__ __launch_bounds__(256) void xpose_kernel(const float* __restrict__ x,
                                                    float* __restrict__ xT,
                                                    float* __restrict__ qn) {
    const int p = blockIdx.x * 256 + threadIdx.x;
    const int cloud = p >> 10, pl = p & 1023;
    const float* xr = x + (size_t)p * F;
    float* xTc = xT + (size_t)cloud * F * PPTS;
    float s = 0.f;
    for (int f = 0; f < F; ++f) {
        const float v = xr[f];
        s = fmaf(v, v, s);
        xTc[(size_t)f * PPTS + pl] = v;
    }
    qn[p] = s;
}

// ---------------------------------------------------------------------------
// Fused kNN v3: 8 rows/block, 256 threads, 4 waves; each wave selects TWO
// rows with INTERLEAVED independent chains (fills the ~45% latency bubbles
// diagnosed in R12-R15: F-flat dur + VALUBusy 54% + occupancy-insensitive).
// Distance: float4 xT candidate loads (XCD-swizzled, L2-resident) +
// ds_read_b128 query fragments. Selection per row = R6-proven algorithm.
// ---------------------------------------------------------------------------
template<int F>
__global__ __launch_bounds__(256, 3) void knn_kernel(const float* __restrict__ x,
                                                     const float* __restrict__ xT,
                                                     const float* __restrict__ qn,
                                                     int* __restrict__ nbr) {
    __shared__ unsigned dmat[RPB][PPTS];     // 32 KB
    __shared__ float    xp[RPB][F];
    __shared__ float    rn[RPB];
    __shared__ unsigned hist[RPB][HPADW];    // 8.7 KB

    const int tid   = threadIdx.x;
    const int lane  = tid & 63;
    const int wave  = tid >> 6;              // 0..3
    // 2048 blocks; XCD swizzle: bid%8 = k -> clouds {k, k+8}
    const int bid   = blockIdx.x;
    const int cloud = (bid & 7) + 8 * (bid >> 10);
    const int pl0   = ((bid >> 3) & 127) * RPB;

    const float* xc = x + (size_t)cloud * PPTS * F;
    for (int i = tid; i < RPB * F; i += 256)
        xp[i / F][i % F] = xc[(size_t)(pl0 + i / F) * F + (i % F)];
    __syncthreads();
    if (tid < RPB) {
        float s = 0.f;
        for (int f = 0; f < F; ++f) { const float v = xp[tid][f]; s = fmaf(v, v, s); }
        rn[tid] = s;
    }
    __syncthreads();

    // ---- distances: candidates q = 4*tid+c, 8 rows ----
    const float* xTc = xT + (size_t)cloud * F * PPTS;
    const float4 qv = *reinterpret_cast<const float4*>(&qn[cloud * PPTS + 4 * tid]);

    float acc[RPB][4];
#pragma unroll
    for (int r = 0; r < RPB; ++r)
#pragma unroll
        for (int c = 0; c < 4; ++c) acc[r][c] = 0.f;

    if constexpr (F % 4 == 0) {
#pragma unroll 1
        for (int f4 = 0; f4 < F / 4; ++f4) {
            float4 vf[4];
#pragma unroll
            for (int j = 0; j < 4; ++j)
                vf[j] = *reinterpret_cast<const float4*>(&xTc[(size_t)(4 * f4 + j) * PPTS + 4 * tid]);
            float4 xr[RPB];
#pragma unroll
            for (int r = 0; r < RPB; ++r) xr[r] = *reinterpret_cast<const float4*>(&xp[r][4 * f4]);
#pragma unroll
            for (int r = 0; r < RPB; ++r) {
                acc[r][0] = fmaf(vf[0].x, xr[r].x, acc[r][0]);
                acc[r][1] = fmaf(vf[0].y, xr[r].x, acc[r][1]);
                acc[r][2] = fmaf(vf[0].z, xr[r].x, acc[r][2]);
                acc[r][3] = fmaf(vf[0].w, xr[r].x, acc[r][3]);
                acc[r][0] = fmaf(vf[1].x, xr[r].y, acc[r][0]);
                acc[r][1] = fmaf(vf[1].y, xr[r].y, acc[r][1]);
                acc[r][2] = fmaf(vf[1].z, xr[r].y, acc[r][2]);
                acc[r][3] = fmaf(vf[1].w, xr[r].y, acc[r][3]);
                acc[r][0] = fmaf(vf[2].x, xr[r].z, acc[r][0]);
                acc[r][1] = fmaf(vf[2].y, xr[r].z, acc[r][1]);
                acc[r][2] = fmaf(vf[2].z, xr[r].z, acc[r][2]);
                acc[r][3] = fmaf(vf[2].w, xr[r].z, acc[r][3]);
                acc[r][0] = fmaf(vf[3].x, xr[r].w, acc[r][0]);
                acc[r][1] = fmaf(vf[3].y, xr[r].w, acc[r][1]);
                acc[r][2] = fmaf(vf[3].z, xr[r].w, acc[r][2]);
                acc[r][3] = fmaf(vf[3].w, xr[r].w, acc[r][3]);
            }
        }
    } else {
        for (int f = 0; f < F; ++f) {
            const float4 v = *reinterpret_cast<const float4*>(&xTc[(size_t)f * PPTS + 4 * tid]);
#pragma unroll
            for (int r = 0; r < RPB; ++r) {
                const float xv = xp[r][f];
                acc[r][0] = fmaf(v.x, xv, acc[r][0]);
                acc[r][1] = fmaf(v.y, xv, acc[r][1]);
                acc[r][2] = fmaf(v.z, xv, acc[r][2]);
                acc[r][3] = fmaf(v.w, xv, acc[r][3]);
            }
        }
    }
#pragma unroll
    for (int r = 0; r < RPB; ++r) {
        uint4 wv;
        float d2;
        d2 = fmaxf(rn[r] + qv.x - 2.f * acc[r][0], 0.f);
        wv.x = (4 * tid + 0 == pl0 + r) ? SELFM : __float_as_uint(d2);
        d2 = fmaxf(rn[r] + qv.y - 2.f * acc[r][1], 0.f);
        wv.y = (4 * tid + 1 == pl0 + r) ? SELFM : __float_as_uint(d2);
        d2 = fmaxf(rn[r] + qv.z - 2.f * acc[r][2], 0.f);
        wv.z = (4 * tid + 2 == pl0 + r) ? SELFM : __float_as_uint(d2);
        d2 = fmaxf(rn[r] + qv.w - 2.f * acc[r][3], 0.f);
        wv.w = (4 * tid + 3 == pl0 + r) ? SELFM : __float_as_uint(d2);
        *reinterpret_cast<uint4*>(&dmat[r][4 * tid]) = wv;
    }
    __syncthreads();

    // ---- selection: wave w handles rows w and w+4, chains interleaved ----
    const int r0 = wave, r1 = wave + 4;
    unsigned* hw0 = hist[r0];
    unsigned* hw1 = hist[r1];
    unsigned bits0[16], bits1[16];
#pragma unroll
    for (int i = 0; i < 16; ++i) {
        bits0[i] = dmat[r0][lane + i * 64];
        bits1[i] = dmat[r1][lane + i * 64];
    }

    unsigned m0 = bits0[0], m1 = bits1[0];
#pragma unroll
    for (int i = 1; i < 16; ++i) { m0 = min(m0, bits0[i]); m1 = min(m1, bits1[i]); }
    unsigned gmin0 = m0, gmin1 = m1;
    unsigned tmax0 = (lane < 32) ? m0 : 0u;
    unsigned tmax1 = (lane < 32) ? m1 : 0u;
#pragma unroll
    for (int off = 1; off < 64; off <<= 1) {
        gmin0 = min(gmin0, (unsigned)__shfl_xor((int)gmin0, off));
        gmin1 = min(gmin1, (unsigned)__shfl_xor((int)gmin1, off));
        tmax0 = max(tmax0, (unsigned)__shfl_xor((int)tmax0, off));
        tmax1 = max(tmax1, (unsigned)__shfl_xor((int)tmax1, off));
    }

    unsigned sm0 = 0u, nam0 = 0xFFFFu, sm1 = 0u, nam1 = 0xFFFFu;
    int R0 = KNB, R1 = KNB;
    unsigned base0 = gmin0, base1 = gmin1;
    int shift0 = 0, shift1 = 0;
    bool do0 = tmax0 > gmin0, do1 = tmax1 > gmin1;
    if (do0) { const unsigned sp = tmax0 - gmin0; const int lg = 31 - __clz(sp); shift0 = lg > 7 ? lg - 7 : 0; }
    if (do1) { const unsigned sp = tmax1 - gmin1; const int lg = 31 - __clz(sp); shift1 = lg > 7 ? lg - 7 : 0; }

#pragma unroll 1
    for (int pass = 0; pass < 2 && (do0 || do1); ++pass) {
        // zero both hists
#pragma unroll
        for (int j = 0; j < 5; ++j) {
            const int k2 = lane + j * 64;
            if (k2 < HPADW) { hw0[k2] = 0u; hw1[k2] = 0u; }
        }
        // bin + atomic, both rows
        if (do0) {
#pragma unroll
            for (int i = 0; i < 16; ++i) {
                if ((nam0 >> i) & 1) {
                    int b = (int)((bits0[i] - base0) >> shift0);
                    b = b > 255 ? 255 : b;
                    atomicAdd(&hw0[hidx(b)], 1u);
                }
            }
        }
        if (do1) {
#pragma unroll
            for (int i = 0; i < 16; ++i) {
                if ((nam1 >> i) & 1) {
                    int b = (int)((bits1[i] - base1) >> shift1);
                    b = b > 255 ? 255 : b;
                    atomicAdd(&hw1[hidx(b)], 1u);
                }
            }
        }
        // read + twin scan
        unsigned h0[4], h1[4];
        int cnt0 = 0, cnt1 = 0;
#pragma unroll
        for (int j = 0; j < 4; ++j) {
            h0[j] = hw0[hidx(lane * 4 + j)]; cnt0 += (int)h0[j];
            h1[j] = hw1[hidx(lane * 4 + j)]; cnt1 += (int)h1[j];
        }
        int inc0 = cnt0, inc1 = cnt1;
#pragma unroll
        for (int off = 1; off < 64; off <<= 1) {
            const int nv0 = __shfl_up(inc0, off);
            const int nv1 = __shfl_up(inc1, off);
            if (lane >= off) { inc0 += nv0; inc1 += nv1; }
        }
        const int pre0 = inc0 - cnt0, pre1 = inc1 - cnt1;
        const bool found0 = do0 && (pre0 < R0 && R0 <= inc0);
        const bool found1 = do1 && (pre1 < R1 && R1 <= inc1);
        unsigned pk0 = 0, pk1 = 0;
        if (found0) {
            int c = pre0, bb = -1, cb = 0; unsigned hbv = 0;
#pragma unroll
            for (int j = 0; j < 4; ++j) {
                if (bb < 0) {
                    if (c + (int)h0[j] >= R0) { bb = lane * 4 + j; hbv = h0[j]; cb = c; }
                    else c += (int)h0[j];
                }
            }
            pk0 = (unsigned)bb | ((unsigned)cb << 8) | (hbv << 16);
        }
        if (found1) {
            int c = pre1, bb = -1, cb = 0; unsigned hbv = 0;
#pragma unroll
            for (int j = 0; j < 4; ++j) {
                if (bb < 0) {
                    if (c + (int)h1[j] >= R1) { bb = lane * 4 + j; hbv = h1[j]; cb = c; }
                    else c += (int)h1[j];
                }
            }
            pk1 = (unsigned)bb | ((unsigned)cb << 8) | (hbv << 16);
        }
        const unsigned long long fm0 = __ballot(found0);
        const unsigned long long fm1 = __ballot(found1);
        pk0 = (unsigned)__shfl((int)pk0, __ffsll(fm0) - 1);
        pk1 = (unsigned)__shfl((int)pk1, __ffsll(fm1) - 1);
        // classify + update row 0
        if (do0) {
            const int bbin = (int)(pk0 & 255u);
            const int cb   = (int)((pk0 >> 8) & 255u);
            const int hb   = (int)(pk0 >> 16);
            const int need = R0 - cb;
            unsigned nnam = 0u;
#pragma unroll
            for (int i = 0; i < 16; ++i) {
                if ((nam0 >> i) & 1) {
                    int b = (int)((bits0[i] - base0) >> shift0);
                    b = b > 255 ? 255 : b;
                    if (b < bbin) sm0 |= 1u << i;
                    else if (b == bbin) nnam |= 1u << i;
                }
            }
            if (hb == need && bbin != 255) { sm0 |= nnam; R0 = 0; do0 = false; }
            else {
                nam0 = nnam; R0 = need;
                if (R0 <= 4 || shift0 == 0) do0 = false;
                else { base0 += (unsigned)bbin << shift0; shift0 = shift0 > 8 ? shift0 - 8 : 0; }
            }
        }
        // classify + update row 1
        if (do1) {
            const int bbin = (int)(pk1 & 255u);
            const int cb   = (int)((pk1 >> 8) & 255u);
            const int hb   = (int)(pk1 >> 16);
            const int need = R1 - cb;
            unsigned nnam = 0u;
#pragma unroll
            for (int i = 0; i < 16; ++i) {
                if ((nam1 >> i) & 1) {
                    int b = (int)((bits1[i] - base1) >> shift1);
                    b = b > 255 ? 255 : b;
                    if (b < bbin) sm1 |= 1u << i;
                    else if (b == bbin) nnam |= 1u << i;
                }
            }
            if (hb == need && bbin != 255) { sm1 |= nnam; R1 = 0; do1 = false; }
            else {
                nam1 = nnam; R1 = need;
                if (R1 <= 4 || shift1 == 0) do1 = false;
                else { base1 += (unsigned)bbin << shift1; shift1 = shift1 > 8 ? shift1 - 8 : 0; }
            }
        }
    }

    // value-group extraction, row 0 then row 1 (exact; usually <=2 groups)
#pragma unroll 1
    while (R0 > 0) {
        unsigned lmin = 0xFFFFFFFFu;
#pragma unroll
        for (int i = 0; i < 16; ++i)
            if ((nam0 >> i) & 1) lmin = min(lmin, bits0[i]);
        unsigned vmin = lmin;
#pragma unroll
        for (int off = 1; off < 64; off <<= 1)
            vmin = min(vmin, (unsigned)__shfl_xor((int)vmin, off));
        unsigned eq = 0u;
#pragma unroll
        for (int i = 0; i < 16; ++i)
            if (((nam0 >> i) & 1) && bits0[i] == vmin) eq |= 1u << i;
        int tot = __popc(eq);
#pragma unroll
        for (int off = 1; off < 64; off <<= 1) tot += __shfl_xor(tot, off);
        if (tot <= R0) { sm0 |= eq; nam0 &= ~eq; R0 -= tot; }
        else {
#pragma unroll
            for (int i = 0; i < 16; ++i) {
                if (R0 > 0) {
                    const bool c2 = (eq >> i) & 1;
                    const unsigned long long mb = __ballot(c2);
                    const int t2 = (int)__popcll(mb);
                    if (t2 <= R0) { if (c2) sm0 |= 1u << i; R0 -= t2; }
                    else {
                        const unsigned long long lower = mb & ((1ull << lane) - 1ull);
                        if (c2 && (int)__popcll(lower) < R0) sm0 |= 1u << i;
                        R0 = 0;
                    }
                }
            }
        }
    }
#pragma unroll 1
    while (R1 > 0) {
        unsigned lmin = 0xFFFFFFFFu;
#pragma unroll
        for (int i = 0; i < 16; ++i)
            if ((nam1 >> i) & 1) lmin = min(lmin, bits1[i]);
        unsigned vmin = lmin;
#pragma unroll
        for (int off = 1; off < 64; off <<= 1)
            vmin = min(vmin, (unsigned)__shfl_xor((int)vmin, off));
        unsigned eq = 0u;
#pragma unroll
        for (int i = 0; i < 16; ++i)
            if (((nam1 >> i) & 1) && bits1[i] == vmin) eq |= 1u << i;
        int tot = __popc(eq);
#pragma unroll
        for (int off = 1; off < 64; off <<= 1) tot += __shfl_xor(tot, off);
        if (tot <= R1) { sm1 |= eq; nam1 &= ~eq; R1 -= tot; }
        else {
#pragma unroll
            for (int i = 0; i < 16; ++i) {
                if (R1 > 0) {
                    const bool c2 = (eq >> i) & 1;
                    const unsigned long long mb = __ballot(c2);
                    const int t2 = (int)__popcll(mb);
                    if (t2 <= R1) { if (c2) sm1 |= 1u << i; R1 -= t2; }
                    else {
                        const unsigned long long lower = mb & ((1ull << lane) - 1ull);
                        if (c2 && (int)__popcll(lower) < R1) sm1 |= 1u << i;
                        R1 = 0;
                    }
                }
            }
        }
    }

    // emit row 0
    {
        int* out = nbr + (size_t)(cloud * PPTS + pl0 + r0) * KNB;
        int tot = 0;
#pragma unroll
        for (int i = 0; i < 16; ++i) {
            const bool c2 = (sm0 >> i) & 1;
            const unsigned long long mb = __ballot(c2);
            if (c2) {
                const int slot = tot + (int)__popcll(mb & ((1ull << lane) - 1ull));
                if (slot < KNB) out[slot] = cloud * PPTS + lane + i * 64;
            }
            tot += (int)__popcll(mb);
        }
        if (lane == 0)
            for (int s = tot; s < KNB; ++s) out[s] = cloud * PPTS + pl0 + r0;
    }
    // emit row 1
    {
        int* out = nbr + (size_t)(cloud * PPTS + pl0 + r1) * KNB;
        int tot = 0;
#pragma unroll
        for (int i = 0; i < 16; ++i) {
            const bool c2 = (sm1 >> i) & 1;
            const unsigned long long mb = __ballot(c2);
            if (c2) {
                const int slot = tot + (int)__popcll(mb & ((1ull << lane) - 1ull));
                if (slot < KNB) out[slot] = cloud * PPTS + lane + i * 64;
            }
            tot += (int)__popcll(mb);
        }
        if (lane == 0)
            for (int s = tot; s < KNB; ++s) out[s] = cloud * PPTS + pl0 + r1;
    }
}

// ---------------------------------------------------------------------------
// Edge GEMM: A = x @ (W_top - W_bot) + b ; Bm = x @ W_bot
// ---------------------------------------------------------------------------
template<int F, int FO>
__global__ __launch_bounds__(256) void edge_gemm_kernel(const float* __restrict__ x,
                                                        const float* __restrict__ W,
                                                        const float* __restrict__ bias,
                                                        float* __restrict__ A,
                                                        float* __restrict__ Bm) {
    constexpr int RT  = 16;
    constexpr int RS  = 256 / FO;
    constexpr int RPT = RT / RS;
    __shared__ float xs[RT][F];
    const int tid = threadIdx.x;
    const int n0  = blockIdx.x * RT;
    for (int i = tid; i < RT * F; i += 256)
        xs[i / F][i % F] = x[(size_t)n0 * F + i];
    __syncthreads();

    const int o  = tid % FO;
    const int r0 = tid / FO;
    float accA[RPT], accB[RPT];
#pragma unroll
    for (int i = 0; i < RPT; ++i) { accA[i] = 0.f; accB[i] = 0.f; }

    for (int f = 0; f < F; ++f) {
        const float wt = W[(size_t)f * FO + o];
        const float wb = W[(size_t)(F + f) * FO + o];
        const float wd = wt - wb;
#pragma unroll
        for (int i = 0; i < RPT; ++i) {
            const float xv = xs[r0 + i * RS][f];
            accA[i] = fmaf(xv, wd, accA[i]);
            accB[i] = fmaf(xv, wb, accB[i]);
        }
    }
    const float bo = bias[o];
#pragma unroll
    for (int i = 0; i < RPT; ++i) {
        const size_t row = (size_t)(n0 + r0 + i * RS);
        A[row * FO + o]  = accA[i] + bo;
        Bm[row * FO + o] = accB[i];
    }
}

// ---------------------------------------------------------------------------
// Combine (float4 + XCD swizzle): x_out = relu(A + max_k Bm[nbr])
// ---------------------------------------------------------------------------
template<int FO>
__global__ __launch_bounds__(256) void combine_kernel(const float* __restrict__ A,
                                                      const float* __restrict__ Bm,
                                                      const int* __restrict__ nbr,
                                                      float* __restrict__ xout) {
    constexpr int FO4 = FO / 4;
    const int bid = (int)((blockIdx.x & 7) * (gridDim.x >> 3) + (blockIdx.x >> 3));
    const int idx = bid * 256 + threadIdx.x;
    const int n  = idx / FO4;
    const int o4 = idx % FO4;
    const int* nb = nbr + (size_t)n * KNB;
    const float4* B4 = reinterpret_cast<const float4*>(Bm);
    float4 mx = make_float4(-FLT_MAX, -FLT_MAX, -FLT_MAX, -FLT_MAX);
#pragma unroll 8
    for (int k = 0; k < KNB; ++k) {
        const float4 v = B4[(size_t)nb[k] * FO4 + o4];
        mx.x = fmaxf(mx.x, v.x); mx.y = fmaxf(mx.y, v.y);
        mx.z = fmaxf(mx.z, v.z); mx.w = fmaxf(mx.w, v.w);
    }
    const float4 a = reinterpret_cast<const float4*>(A)[idx];
    float4 rr;
    rr.x = fmaxf(a.x + mx.x, 0.f);
    rr.y = fmaxf(a.y + mx.y, 0.f);
    rr.z = fmaxf(a.z + mx.z, 0.f);
    rr.w = fmaxf(a.w + mx.w, 0.f);
    reinterpret_cast<float4*>(xout)[idx] = rr;
}

// ---------------------------------------------------------------------------
// Classifier GEMM (R15-proven): logits = X @ Wc + bc, 320 threads/block.
// ---------------------------------------------------------------------------
__global__ __launch_bounds__(320) void cls_gemm_kernel(const float* __restrict__ x,
                                                       const float* __restrict__ Wc,
                                                       const float* __restrict__ bc,
                                                       float* __restrict__ logits) {
    constexpr int RT = 16;
    __shared__ float xs[RT][256];
    __shared__ float wsm[256][NCLS];
    const int tid = threadIdx.x;
    const int n0  = blockIdx.x * RT;

    const float4* xsrc = reinterpret_cast<const float4*>(x + (size_t)n0 * 256);
    float4* xdst = reinterpret_cast<float4*>(&xs[0][0]);
    for (int i = tid; i < RT * 256 / 4; i += 320) xdst[i] = xsrc[i];
    for (int i = tid; i < 256 * NCLS; i += 320) wsm[i / NCLS][i % NCLS] = Wc[i];
    __syncthreads();

    const int o  = tid % NCLS;
    const int rg = tid / NCLS;
    float acc0 = 0.f, acc1 = 0.f;
#pragma unroll 4
    for (int f4 = 0; f4 < 64; ++f4) {
        float wv0 = wsm[4 * f4 + 0][o];
        float wv1 = wsm[4 * f4 + 1][o];
        float wv2 = wsm[4 * f4 + 2][o];
        float wv3 = wsm[4 * f4 + 3][o];
        const float4 xa = *reinterpret_cast<const float4*>(&xs[rg][4 * f4]);
        const float4 xb = *reinterpret_cast<const float4*>(&xs[rg + 8][4 * f4]);
        acc0 = fmaf(xa.x, wv0, acc0); acc0 = fmaf(xa.y, wv1, acc0);
        acc0 = fmaf(xa.z, wv2, acc0); acc0 = fmaf(xa.w, wv3, acc0);
        acc1 = fmaf(xb.x, wv0, acc1); acc1 = fmaf(xb.y, wv1, acc1);
        acc1 = fmaf(xb.z, wv2, acc1); acc1 = fmaf(xb.w, wv3, acc1);
    }
    const float bo = bc[o];
    logits[(size_t)(n0 + rg) * NCLS + o]     = acc0 + bo;
    logits[(size_t)(n0 + rg + 8) * NCLS + o] = acc1 + bo;
}

// ---------------------------------------------------------------------------
// Softmax + per-row loss
// ---------------------------------------------------------------------------
__global__ __launch_bounds__(256) void softmax_loss_kernel(const float* __restrict__ logits,
                                                           const int* __restrict__ target,
                                                           float* __restrict__ probs,
                                                           float* __restrict__ lossbuf) {
    const int tid = threadIdx.x;
    const int lane = tid & 63;
    const int n = blockIdx.x * 4 + (tid >> 6);
    float logit = -FLT_MAX;
    if (lane < NCLS) logit = logits[(size_t)n * NCLS + lane];
    float m = logit;
#pragma unroll
    for (int off = 32; off; off >>= 1) m = fmaxf(m, __shfl_xor(m, off));
    const float e = (lane < NCLS) ? __expf(logit - m) : 0.f;
    float s = e;
#pragma unroll
    for (int off = 32; off; off >>= 1) s += __shfl_xor(s, off);
    if (lane < NCLS) probs[(size_t)n * NCLS + lane] = e / s;
    const float lt = __shfl(logit, target[n]);
    if (lane == 0) lossbuf[n] = logf(s) - (lt - m);
}

__global__ __launch_bounds__(256) void loss_reduce_kernel(const float* __restrict__ lossbuf,
                                                          float* __restrict__ out) {
    __shared__ float s[256];
    float acc = 0.f;
    for (int i = threadIdx.x; i < NPTS; i += 256) acc += lossbuf[i];
    s[threadIdx.x] = acc;
    __syncthreads();
    for (int off = 128; off; off >>= 1) {
        if (threadIdx.x < off) s[threadIdx.x] += s[threadIdx.x + off];
        __syncthreads();
    }
    if (threadIdx.x == 0) out[0] = s[0] / (float)NPTS;
}

extern "C" void kernel_launch(void* const* d_in, const int* in_sizes, int n_in,
                              void* d_out, int out_size, void* d_ws, size_t ws_size,
                              hipStream_t stream) {
    (void)in_sizes; (void)n_in; (void)out_size; (void)ws_size;
    const float* x_in   = (const float*)d_in[0];
    const int*   target = (const int*)d_in[2];
    const float* W1 = (const float*)d_in[3];
    const float* b1 = (const float*)d_in[4];
    const float* W2 = (const float*)d_in[5];
    const float* b2 = (const float*)d_in[6];
    const float* W3 = (const float*)d_in[7];
    const float* b3 = (const float*)d_in[8];
    const float* Wc = (const float*)d_in[9];
    const float* bc = (const float*)d_in[10];

    // proven-safe window [0, 50MB+64KB):
    //   X [0,16M) | A [16,32M) | Bm [32,48M) | nbr [48,50M) | lossbuf [50M,+64K)
    //   xT [32,40M) + qn [40M,+64K) alias dead-Bm during kNN phase
    //   logits [16M,+2.6M) alias dead-A during classifier phase
    char* ws = (char*)d_ws;
    float* X       = (float*)(ws);
    float* A       = (float*)(ws + (size_t)16 * 1024 * 1024);
    float* Bm      = (float*)(ws + (size_t)32 * 1024 * 1024);
    float* xT      = (float*)(ws + (size_t)32 * 1024 * 1024);
    float* qn      = (float*)(ws + (size_t)40 * 1024 * 1024);
    int*   nbr     = (int*)  (ws + (size_t)48 * 1024 * 1024);
    float* lossbuf = (float*)(ws + (size_t)50 * 1024 * 1024);
    float* logits  = (float*)(ws + (size_t)16 * 1024 * 1024);

    float* outF  = (float*)d_out;
    float* probs = outF + 1;

    // ---- layer 1 (3 -> 64) ----
    xpose_kernel<3><<<NPTS / 256, 256, 0, stream>>>(x_in, xT, qn);
    knn_kernel<3><<<NPTS / RPB, 256, 0, stream>>>(x_in, xT, qn, nbr);
    edge_gemm_kernel<3, 64><<<NPTS / 16, 256, 0, stream>>>(x_in, W1, b1, A, Bm);
    combine_kernel<64><<<NPTS * 16 / 256, 256, 0, stream>>>(A, Bm, nbr, X);

    // ---- layer 2 (64 -> 128) ----
    xpose_kernel<64><<<NPTS / 256, 256, 0, stream>>>(X, xT, qn);
    knn_kernel<64><<<NPTS / RPB, 256, 0, stream>>>(X, xT, qn, nbr);
    edge_gemm_kernel<64, 128><<<NPTS / 16, 256, 0, stream>>>(X, W2, b2, A, Bm);
    combine_kernel<128><<<NPTS * 32 / 256, 256, 0, stream>>>(A, Bm, nbr, X);

    // ---- layer 3 (128 -> 256) ----
    xpose_kernel<128><<<NPTS / 256, 256, 0, stream>>>(X, xT, qn);
    knn_kernel<128><<<NPTS / RPB, 256, 0, stream>>>(X, xT, qn, nbr);
    edge_gemm_kernel<128, 256><<<NPTS / 16, 256, 0, stream>>>(X, W3, b3, A, Bm);
    combine_kernel<256><<<NPTS * 64 / 256, 256, 0, stream>>>(A, Bm, nbr, X);

    // ---- classifier + loss ----
    cls_gemm_kernel<<<NPTS / 16, 320, 0, stream>>>(X, Wc, bc, logits);
    softmax_loss_kernel<<<NPTS / 4, 256, 0, stream>>>(logits, target, probs, lossbuf);
    loss_reduce_kernel<<<1, 256, 0, stream>>>(lossbuf, outF);
}

// Round 17
// 367.586 us; speedup vs baseline: 1.0459x; 1.0459x over previous
//
#include <hip/hip_runtime.h>
#include <float.h>
#include <math.h>

#define BCLOUDS 16
#define PPTS    1024
#define NPTS    (BCLOUDS * PPTS)
#define KNB     32
#define NCLS    40
#define RPB     4                  // rows per knn block (= waves per block)
#define NBIN    256
#define HPADW   (NBIN + NBIN / 16)
#define SELFM   0xFFFFFFFFu        // self marker: above every real distance bit pattern

__device__ __forceinline__ int hidx(int b) { return b + (b >> 4); }

// ---------------------------------------------------------------------------
// Transpose + norms: xT[cloud][f][p] = x[cloud*1024+p][f]; qn[p] = |x_p|^2
// ---------------------------------------------------------------------------
template<int F>
__global__ __launch_bounds__(256) void xpose_kernel(const float* __restrict__ x,
                                                    float* __restrict__ xT,
                                                    float* __restrict__ qn) {
    const int p = blockIdx.x * 256 + threadIdx.x;
    const int cloud = p >> 10, pl = p & 1023;
    const float* xr = x + (size_t)p * F;
    float* xTc = xT + (size_t)cloud * F * PPTS;
    float s = 0.f;
    for (int f = 0; f < F; ++f) {
        const float v = xr[f];
        s = fmaf(v, v, s);
        xTc[(size_t)f * PPTS + pl] = v;
    }
    qn[p] = s;
}

// ---------------------------------------------------------------------------
// Fused kNN (R13/R15 structure EXACTLY; one change: launch_bounds min-waves
// 6 -> 2). R5-R16 forensics: __launch_bounds__(...,6) forced VGPR_Count=40,
// spilling bits[16]/bin[16]/acc[4][4] to SCRATCH -> every selection slot-loop
// iteration became a ~200-400cy scratch fill -> the F/occupancy/structure-
// invariant 112us wall. Let the allocator keep state in registers.
// ---------------------------------------------------------------------------
template<int F>
__global__ __launch_bounds__(256, 2) void knn_kernel(const float* __restrict__ x,
                                                     const float* __restrict__ xT,
                                                     const float* __restrict__ qn,
                                                     int* __restrict__ nbr) {
    __shared__ unsigned dmat[RPB][PPTS];
    __shared__ float    xp[RPB][F];
    __shared__ float    rn[RPB];
    __shared__ unsigned hist[RPB][HPADW];

    const int tid   = threadIdx.x;
    const int lane  = tid & 63;
    const int wave  = tid >> 6;            // 0..3
    const int bid   = blockIdx.x;
    const int cloud = (bid & 7) + 8 * (bid >> 11);
    const int pl0   = ((bid >> 3) & 255) * RPB;

    const float* xc = x + (size_t)cloud * PPTS * F;
    for (int i = tid; i < RPB * F; i += 256)
        xp[i / F][i % F] = xc[(size_t)(pl0 + i / F) * F + (i % F)];
    __syncthreads();
    if (tid < RPB) {
        float s = 0.f;
        for (int f = 0; f < F; ++f) { const float v = xp[tid][f]; s = fmaf(v, v, s); }
        rn[tid] = s;
    }
    __syncthreads();

    const float* xTc = xT + (size_t)cloud * F * PPTS;
    const float4 qv = *reinterpret_cast<const float4*>(&qn[cloud * PPTS + 4 * tid]);

    float acc[RPB][4];
#pragma unroll
    for (int r = 0; r < RPB; ++r)
#pragma unroll
        for (int c = 0; c < 4; ++c) acc[r][c] = 0.f;

    if constexpr (F % 4 == 0) {
#pragma unroll 2
        for (int f4 = 0; f4 < F / 4; ++f4) {
            float4 vf[4];
#pragma unroll
            for (int j = 0; j < 4; ++j)
                vf[j] = *reinterpret_cast<const float4*>(&xTc[(size_t)(4 * f4 + j) * PPTS + 4 * tid]);
            float4 xr[RPB];
#pragma unroll
            for (int r = 0; r < RPB; ++r) xr[r] = *reinterpret_cast<const float4*>(&xp[r][4 * f4]);
#pragma unroll
            for (int r = 0; r < RPB; ++r) {
                acc[r][0] = fmaf(vf[0].x, xr[r].x, acc[r][0]);
                acc[r][1] = fmaf(vf[0].y, xr[r].x, acc[r][1]);
                acc[r][2] = fmaf(vf[0].z, xr[r].x, acc[r][2]);
                acc[r][3] = fmaf(vf[0].w, xr[r].x, acc[r][3]);
                acc[r][0] = fmaf(vf[1].x, xr[r].y, acc[r][0]);
                acc[r][1] = fmaf(vf[1].y, xr[r].y, acc[r][1]);
                acc[r][2] = fmaf(vf[1].z, xr[r].y, acc[r][2]);
                acc[r][3] = fmaf(vf[1].w, xr[r].y, acc[r][3]);
                acc[r][0] = fmaf(vf[2].x, xr[r].z, acc[r][0]);
                acc[r][1] = fmaf(vf[2].y, xr[r].z, acc[r][1]);
                acc[r][2] = fmaf(vf[2].z, xr[r].z, acc[r][2]);
                acc[r][3] = fmaf(vf[2].w, xr[r].z, acc[r][3]);
                acc[r][0] = fmaf(vf[3].x, xr[r].w, acc[r][0]);
                acc[r][1] = fmaf(vf[3].y, xr[r].w, acc[r][1]);
                acc[r][2] = fmaf(vf[3].z, xr[r].w, acc[r][2]);
                acc[r][3] = fmaf(vf[3].w, xr[r].w, acc[r][3]);
            }
        }
    } else {
        for (int f = 0; f < F; ++f) {
            const float4 v = *reinterpret_cast<const float4*>(&xTc[(size_t)f * PPTS + 4 * tid]);
#pragma unroll
            for (int r = 0; r < RPB; ++r) {
                const float xv = xp[r][f];
                acc[r][0] = fmaf(v.x, xv, acc[r][0]);
                acc[r][1] = fmaf(v.y, xv, acc[r][1]);
                acc[r][2] = fmaf(v.z, xv, acc[r][2]);
                acc[r][3] = fmaf(v.w, xv, acc[r][3]);
            }
        }
    }
#pragma unroll
    for (int r = 0; r < RPB; ++r) {
        uint4 wv;
        float d2;
        d2 = fmaxf(rn[r] + qv.x - 2.f * acc[r][0], 0.f);
        wv.x = (4 * tid + 0 == pl0 + r) ? SELFM : __float_as_uint(d2);
        d2 = fmaxf(rn[r] + qv.y - 2.f * acc[r][1], 0.f);
        wv.y = (4 * tid + 1 == pl0 + r) ? SELFM : __float_as_uint(d2);
        d2 = fmaxf(rn[r] + qv.z - 2.f * acc[r][2], 0.f);
        wv.z = (4 * tid + 2 == pl0 + r) ? SELFM : __float_as_uint(d2);
        d2 = fmaxf(rn[r] + qv.w - 2.f * acc[r][3], 0.f);
        wv.w = (4 * tid + 3 == pl0 + r) ? SELFM : __float_as_uint(d2);
        *reinterpret_cast<uint4*>(&dmat[r][4 * tid]) = wv;
    }
    __syncthreads();

    // ---- selection (R6-proven verbatim): wave w handles row w ----
    unsigned* hw = hist[wave];
    const int r = wave;
    unsigned bits[16];
#pragma unroll
    for (int i = 0; i < 16; ++i) bits[i] = dmat[r][lane + i * 64];

    unsigned m = bits[0];
#pragma unroll
    for (int i = 1; i < 16; ++i) m = min(m, bits[i]);
    unsigned gmin = m;
    unsigned tmax = (lane < 32) ? m : 0u;
#pragma unroll
    for (int off = 1; off < 64; off <<= 1) {
        gmin = min(gmin, (unsigned)__shfl_xor((int)gmin, off));
        tmax = max(tmax, (unsigned)__shfl_xor((int)tmax, off));
    }

    unsigned sm = 0u, nam = 0xFFFFu;
    int R = KNB;
    unsigned base = gmin;
    int shift = 0;
    bool do_hist = tmax > gmin;
    if (do_hist) {
        const unsigned span = tmax - gmin;
        const int lg = 31 - __clz(span);
        shift = lg > 7 ? lg - 7 : 0;
    }

#pragma unroll 1
    for (int pass = 0; pass < 2 && do_hist; ++pass) {
        int bin[16];
#pragma unroll
        for (int j = 0; j < 5; ++j) { const int k2 = lane + j * 64; if (k2 < HPADW) hw[k2] = 0u; }
#pragma unroll
        for (int i = 0; i < 16; ++i) {
            if ((nam >> i) & 1) {
                const unsigned d = bits[i] - base;
                int b = (int)(d >> shift);
                b = b > 255 ? 255 : b;
                bin[i] = b;
                atomicAdd(&hw[hidx(b)], 1u);
            } else bin[i] = 256;
        }
        unsigned h[4];
        int cnt = 0;
#pragma unroll
        for (int j = 0; j < 4; ++j) { h[j] = hw[hidx(lane * 4 + j)]; cnt += (int)h[j]; }
        int inc = cnt;
#pragma unroll
        for (int off = 1; off < 64; off <<= 1) {
            const int nv = __shfl_up(inc, off);
            if (lane >= off) inc += nv;
        }
        const int pre = inc - cnt;
        const bool found = (pre < R && R <= inc);
        unsigned pk = 0;
        if (found) {
            int c = pre, bb = -1, cb = 0; unsigned hbv = 0;
#pragma unroll
            for (int j = 0; j < 4; ++j) {
                if (bb < 0) {
                    if (c + (int)h[j] >= R) { bb = lane * 4 + j; hbv = h[j]; cb = c; }
                    else c += (int)h[j];
                }
            }
            pk = (unsigned)bb | ((unsigned)cb << 8) | (hbv << 16);
        }
        const unsigned long long fm = __ballot(found);
        pk = (unsigned)__shfl((int)pk, __ffsll(fm) - 1);
        const int bbin = (int)(pk & 255u);
        const int cb   = (int)((pk >> 8) & 255u);
        const int hb   = (int)(pk >> 16);
        const int need = R - cb;
        unsigned nnam = 0u;
#pragma unroll
        for (int i = 0; i < 16; ++i) {
            if (bin[i] < bbin) sm |= 1u << i;
            else if (bin[i] == bbin) nnam |= 1u << i;
        }
        if (hb == need && bbin != 255) {
            sm |= nnam; R = 0; do_hist = false;
        } else {
            nam = nnam; R = need;
            if (R <= 4 || shift == 0) do_hist = false;
            else {
                base += (unsigned)bbin << shift;
                shift = shift > 8 ? shift - 8 : 0;
            }
        }
    }

#pragma unroll 1
    while (R > 0) {
        unsigned lmin = 0xFFFFFFFFu;
#pragma unroll
        for (int i = 0; i < 16; ++i)
            if ((nam >> i) & 1) lmin = min(lmin, bits[i]);
        unsigned vmin = lmin;
#pragma unroll
        for (int off = 1; off < 64; off <<= 1)
            vmin = min(vmin, (unsigned)__shfl_xor((int)vmin, off));
        unsigned eq = 0u;
#pragma unroll
        for (int i = 0; i < 16; ++i)
            if (((nam >> i) & 1) && bits[i] == vmin) eq |= 1u << i;
        int tot = __popc(eq);
#pragma unroll
        for (int off = 1; off < 64; off <<= 1) tot += __shfl_xor(tot, off);
        if (tot <= R) { sm |= eq; nam &= ~eq; R -= tot; }
        else {
#pragma unroll
            for (int i = 0; i < 16; ++i) {
                if (R > 0) {
                    const bool c2 = (eq >> i) & 1;
                    const unsigned long long mb = __ballot(c2);
                    const int t2 = (int)__popcll(mb);
                    if (t2 <= R) { if (c2) sm |= 1u << i; R -= t2; }
                    else {
                        const unsigned long long lower = mb & ((1ull << lane) - 1ull);
                        if (c2 && (int)__popcll(lower) < R) sm |= 1u << i;
                        R = 0;
                    }
                }
            }
        }
    }

    int* out = nbr + (size_t)(cloud * PPTS + pl0 + r) * KNB;
    int tot = 0;
#pragma unroll
    for (int i = 0; i < 16; ++i) {
        const bool c2 = (sm >> i) & 1;
        const unsigned long long mb = __ballot(c2);
        if (c2) {
            const int slot = tot + (int)__popcll(mb & ((1ull << lane) - 1ull));
            if (slot < KNB) out[slot] = cloud * PPTS + lane + i * 64;
        }
        tot += (int)__popcll(mb);
    }
    if (lane == 0)
        for (int s = tot; s < KNB; ++s) out[s] = cloud * PPTS + pl0 + r;
}

// ---------------------------------------------------------------------------
// Edge GEMM: A = x @ (W_top - W_bot) + b ; Bm = x @ W_bot
// ---------------------------------------------------------------------------
template<int F, int FO>
__global__ __launch_bounds__(256) void edge_gemm_kernel(const float* __restrict__ x,
                                                        const float* __restrict__ W,
                                                        const float* __restrict__ bias,
                                                        float* __restrict__ A,
                                                        float* __restrict__ Bm) {
    constexpr int RT  = 16;
    constexpr int RS  = 256 / FO;
    constexpr int RPT = RT / RS;
    __shared__ float xs[RT][F];
    const int tid = threadIdx.x;
    const int n0  = blockIdx.x * RT;
    for (int i = tid; i < RT * F; i += 256)
        xs[i / F][i % F] = x[(size_t)n0 * F + i];
    __syncthreads();

    const int o  = tid % FO;
    const int r0 = tid / FO;
    float accA[RPT], accB[RPT];
#pragma unroll
    for (int i = 0; i < RPT; ++i) { accA[i] = 0.f; accB[i] = 0.f; }

    for (int f = 0; f < F; ++f) {
        const float wt = W[(size_t)f * FO + o];
        const float wb = W[(size_t)(F + f) * FO + o];
        const float wd = wt - wb;
#pragma unroll
        for (int i = 0; i < RPT; ++i) {
            const float xv = xs[r0 + i * RS][f];
            accA[i] = fmaf(xv, wd, accA[i]);
            accB[i] = fmaf(xv, wb, accB[i]);
        }
    }
    const float bo = bias[o];
#pragma unroll
    for (int i = 0; i < RPT; ++i) {
        const size_t row = (size_t)(n0 + r0 + i * RS);
        A[row * FO + o]  = accA[i] + bo;
        Bm[row * FO + o] = accB[i];
    }
}

// ---------------------------------------------------------------------------
// Combine (float4 + XCD swizzle): x_out = relu(A + max_k Bm[nbr])
// ---------------------------------------------------------------------------
template<int FO>
__global__ __launch_bounds__(256) void combine_kernel(const float* __restrict__ A,
                                                      const float* __restrict__ Bm,
                                                      const int* __restrict__ nbr,
                                                      float* __restrict__ xout) {
    constexpr int FO4 = FO / 4;
    const int bid = (int)((blockIdx.x & 7) * (gridDim.x >> 3) + (blockIdx.x >> 3));
    const int idx = bid * 256 + threadIdx.x;
    const int n  = idx / FO4;
    const int o4 = idx % FO4;
    const int* nb = nbr + (size_t)n * KNB;
    const float4* B4 = reinterpret_cast<const float4*>(Bm);
    float4 mx = make_float4(-FLT_MAX, -FLT_MAX, -FLT_MAX, -FLT_MAX);
#pragma unroll 8
    for (int k = 0; k < KNB; ++k) {
        const float4 v = B4[(size_t)nb[k] * FO4 + o4];
        mx.x = fmaxf(mx.x, v.x); mx.y = fmaxf(mx.y, v.y);
        mx.z = fmaxf(mx.z, v.z); mx.w = fmaxf(mx.w, v.w);
    }
    const float4 a = reinterpret_cast<const float4*>(A)[idx];
    float4 rr;
    rr.x = fmaxf(a.x + mx.x, 0.f);
    rr.y = fmaxf(a.y + mx.y, 0.f);
    rr.z = fmaxf(a.z + mx.z, 0.f);
    rr.w = fmaxf(a.w + mx.w, 0.f);
    reinterpret_cast<float4*>(xout)[idx] = rr;
}

// ---------------------------------------------------------------------------
// Classifier GEMM (R15-proven): logits = X @ Wc + bc, 320 threads/block.
// ---------------------------------------------------------------------------
__global__ __launch_bounds__(320) void cls_gemm_kernel(const float* __restrict__ x,
                                                       const float* __restrict__ Wc,
                                                       const float* __restrict__ bc,
                                                       float* __restrict__ logits) {
    constexpr int RT = 16;
    __shared__ float xs[RT][256];
    __shared__ float wsm[256][NCLS];
    const int tid = threadIdx.x;
    const int n0  = blockIdx.x * RT;

    const float4* xsrc = reinterpret_cast<const float4*>(x + (size_t)n0 * 256);
    float4* xdst = reinterpret_cast<float4*>(&xs[0][0]);
    for (int i = tid; i < RT * 256 / 4; i += 320) xdst[i] = xsrc[i];
    for (int i = tid; i < 256 * NCLS; i += 320) wsm[i / NCLS][i % NCLS] = Wc[i];
    __syncthreads();

    const int o  = tid % NCLS;
    const int rg = tid / NCLS;
    float acc0 = 0.f, acc1 = 0.f;
#pragma unroll 4
    for (int f4 = 0; f4 < 64; ++f4) {
        float wv0 = wsm[4 * f4 + 0][o];
        float wv1 = wsm[4 * f4 + 1][o];
        float wv2 = wsm[4 * f4 + 2][o];
        float wv3 = wsm[4 * f4 + 3][o];
        const float4 xa = *reinterpret_cast<const float4*>(&xs[rg][4 * f4]);
        const float4 xb = *reinterpret_cast<const float4*>(&xs[rg + 8][4 * f4]);
        acc0 = fmaf(xa.x, wv0, acc0); acc0 = fmaf(xa.y, wv1, acc0);
        acc0 = fmaf(xa.z, wv2, acc0); acc0 = fmaf(xa.w, wv3, acc0);
        acc1 = fmaf(xb.x, wv0, acc1); acc1 = fmaf(xb.y, wv1, acc1);
        acc1 = fmaf(xb.z, wv2, acc1); acc1 = fmaf(xb.w, wv3, acc1);
    }
    const float bo = bc[o];
    logits[(size_t)(n0 + rg) * NCLS + o]     = acc0 + bo;
    logits[(size_t)(n0 + rg + 8) * NCLS + o] = acc1 + bo;
}

// ---------------------------------------------------------------------------
// Softmax + per-row loss
// ---------------------------------------------------------------------------
__global__ __launch_bounds__(256) void softmax_loss_kernel(const float* __restrict__ logits,
                                                           const int* __restrict__ target,
                                                           float* __restrict__ probs,
                                                           float* __restrict__ lossbuf) {
    const int tid = threadIdx.x;
    const int lane = tid & 63;
    const int n = blockIdx.x * 4 + (tid >> 6);
    float logit = -FLT_MAX;
    if (lane < NCLS) logit = logits[(size_t)n * NCLS + lane];
    float m = logit;
#pragma unroll
    for (int off = 32; off; off >>= 1) m = fmaxf(m, __shfl_xor(m, off));
    const float e = (lane < NCLS) ? __expf(logit - m) : 0.f;
    float s = e;
#pragma unroll
    for (int off = 32; off; off >>= 1) s += __shfl_xor(s, off);
    if (lane < NCLS) probs[(size_t)n * NCLS + lane] = e / s;
    const float lt = __shfl(logit, target[n]);
    if (lane == 0) lossbuf[n] = logf(s) - (lt - m);
}

__global__ __launch_bounds__(256) void loss_reduce_kernel(const float* __restrict__ lossbuf,
                                                          float* __restrict__ out) {
    __shared__ float s[256];
    float acc = 0.f;
    for (int i = threadIdx.x; i < NPTS; i += 256) acc += lossbuf[i];
    s[threadIdx.x] = acc;
    __syncthreads();
    for (int off = 128; off; off >>= 1) {
        if (threadIdx.x < off) s[threadIdx.x] += s[threadIdx.x + off];
        __syncthreads();
    }
    if (threadIdx.x == 0) out[0] = s[0] / (float)NPTS;
}

extern "C" void kernel_launch(void* const* d_in, const int* in_sizes, int n_in,
                              void* d_out, int out_size, void* d_ws, size_t ws_size,
                              hipStream_t stream) {
    (void)in_sizes; (void)n_in; (void)out_size; (void)ws_size;
    const float* x_in   = (const float*)d_in[0];
    const int*   target = (const int*)d_in[2];
    const float* W1 = (const float*)d_in[3];
    const float* b1 = (const float*)d_in[4];
    const float* W2 = (const float*)d_in[5];
    const float* b2 = (const float*)d_in[6];
    const float* W3 = (const float*)d_in[7];
    const float* b3 = (const float*)d_in[8];
    const float* Wc = (const float*)d_in[9];
    const float* bc = (const float*)d_in[10];

    // proven-safe window [0, 50MB+64KB):
    //   X [0,16M) | A [16,32M) | Bm [32,48M) | nbr [48,50M) | lossbuf [50M,+64K)
    //   xT [32,40M) + qn [40M,+64K) alias dead-Bm during kNN phase
    //   logits [16M,+2.6M) alias dead-A during classifier phase
    char* ws = (char*)d_ws;
    float* X       = (float*)(ws);
    float* A       = (float*)(ws + (size_t)16 * 1024 * 1024);
    float* Bm      = (float*)(ws + (size_t)32 * 1024 * 1024);
    float* xT      = (float*)(ws + (size_t)32 * 1024 * 1024);
    float* qn      = (float*)(ws + (size_t)40 * 1024 * 1024);
    int*   nbr     = (int*)  (ws + (size_t)48 * 1024 * 1024);
    float* lossbuf = (float*)(ws + (size_t)50 * 1024 * 1024);
    float* logits  = (float*)(ws + (size_t)16 * 1024 * 1024);

    float* outF  = (float*)d_out;
    float* probs = outF + 1;

    // ---- layer 1 (3 -> 64) ----
    xpose_kernel<3><<<NPTS / 256, 256, 0, stream>>>(x_in, xT, qn);
    knn_kernel<3><<<NPTS / RPB, 256, 0, stream>>>(x_in, xT, qn, nbr);
    edge_gemm_kernel<3, 64><<<NPTS / 16, 256, 0, stream>>>(x_in, W1, b1, A, Bm);
    combine_kernel<64><<<NPTS * 16 / 256, 256, 0, stream>>>(A, Bm, nbr, X);

    // ---- layer 2 (64 -> 128) ----
    xpose_kernel<64><<<NPTS / 256, 256, 0, stream>>>(X, xT, qn);
    knn_kernel<64><<<NPTS / RPB, 256, 0, stream>>>(X, xT, qn, nbr);
    edge_gemm_kernel<64, 128><<<NPTS / 16, 256, 0, stream>>>(X, W2, b2, A, Bm);
    combine_kernel<128><<<NPTS * 32 / 256, 256, 0, stream>>>(A, Bm, nbr, X);

    // ---- layer 3 (128 -> 256) ----
    xpose_kernel<128><<<NPTS / 256, 256, 0, stream>>>(X, xT, qn);
    knn_kernel<128><<<NPTS / RPB, 256, 0, stream>>>(X, xT, qn, nbr);
    edge_gemm_kernel<128, 256><<<NPTS / 16, 256, 0, stream>>>(X, W3, b3, A, Bm);
    combine_kernel<256><<<NPTS * 64 / 256, 256, 0, stream>>>(A, Bm, nbr, X);

    // ---- classifier + loss ----
    cls_gemm_kernel<<<NPTS / 16, 320, 0, stream>>>(X, Wc, bc, logits);
    softmax_loss_kernel<<<NPTS / 4, 256, 0, stream>>>(logits, target, probs, lossbuf);
    loss_reduce_kernel<<<1, 256, 0, stream>>>(lossbuf, outF);
}

// Round 18
// 345.168 us; speedup vs baseline: 1.1139x; 1.0649x over previous
//
#include <hip/hip_runtime.h>
#include <float.h>
#include <math.h>

#define BCLOUDS 16
#define PPTS    1024
#define NPTS    (BCLOUDS * PPTS)
#define KNB     32
#define NCLS    40
#define RPB     4                  // rows per knn block (= waves per block)
#define KNNBLK  (NPTS / RPB)       // 4096 knn blocks
#define EDGEBLK (NPTS / 16)        // 1024 edge blocks
#define NBIN    256
#define HPADW   (NBIN + NBIN / 16)
#define SELFM   0xFFFFFFFFu        // self marker: above every real distance bit pattern

__device__ __forceinline__ int hidx(int b) { return b + (b >> 4); }

// ---------------------------------------------------------------------------
// Transpose + norms: xT[cloud][f][p] = x[cloud*1024+p][f]; qn[p] = |x_p|^2
// qn shares the lossbuf 64KB slot (disjoint lifetimes).
// ---------------------------------------------------------------------------
template<int F>
__global__ __launch_bounds__(256) void xpose_kernel(const float* __restrict__ x,
                                                    float* __restrict__ xT,
                                                    float* __restrict__ qn) {
    const int p = blockIdx.x * 256 + threadIdx.x;
    const int cloud = p >> 10, pl = p & 1023;
    const float* xr = x + (size_t)p * F;
    float* xTc = xT + (size_t)cloud * F * PPTS;
    float s = 0.f;
    for (int f = 0; f < F; ++f) {
        const float v = xr[f];
        s = fmaf(v, v, s);
        xTc[(size_t)f * PPTS + pl] = v;
    }
    qn[p] = s;
}

// ---------------------------------------------------------------------------
// FUSED kNN + edge-GEMM dispatch (block-range fusion):
//   blocks [0, 4096): R17's kNN body (XCD swizzle, float4 xT loads,
//                     R6-proven selection) -> nbr
//   blocks [4096, 5120): edge GEMM A = x@(Wt-Wb)+b, Bm = x@Wb
// Edge blocks depend only on x (prev-layer X) — independent of nbr — and
// execute in the kNN waves' ~47% idle issue slots (selection latency-bound,
// 7 structural levers measured invariant R12-R17).
// ---------------------------------------------------------------------------
template<int F, int FO>
__global__ __launch_bounds__(256, 2) void knn_edge_kernel(const float* __restrict__ x,
                                                          const float* __restrict__ xT,
                                                          const float* __restrict__ qn,
                                                          int* __restrict__ nbr,
                                                          const float* __restrict__ W,
                                                          const float* __restrict__ bias,
                                                          float* __restrict__ A,
                                                          float* __restrict__ Bm) {
    __shared__ unsigned dmat[RPB][PPTS];     // 16 KB (knn path)
    __shared__ float    xp[RPB][F];
    __shared__ float    rn[RPB];
    __shared__ unsigned hist[RPB][HPADW];    // 4.25 KB (knn path)
    __shared__ float    xs[16][F];           // 8 KB max (edge path)

    const int tid = threadIdx.x;

    if (blockIdx.x >= KNNBLK) {
        // ================= edge GEMM path (R17 edge_gemm body) =================
        constexpr int RT  = 16;
        constexpr int RS  = 256 / FO;
        constexpr int RPT = RT / RS;
        const int n0 = (int)(blockIdx.x - KNNBLK) * RT;
        for (int i = tid; i < RT * F; i += 256)
            xs[i / F][i % F] = x[(size_t)n0 * F + i];
        __syncthreads();

        const int o  = tid % FO;
        const int r0 = tid / FO;
        float accA[RPT], accB[RPT];
#pragma unroll
        for (int i = 0; i < RPT; ++i) { accA[i] = 0.f; accB[i] = 0.f; }

        for (int f = 0; f < F; ++f) {
            const float wt = W[(size_t)f * FO + o];
            const float wb = W[(size_t)(F + f) * FO + o];
            const float wd = wt - wb;
#pragma unroll
            for (int i = 0; i < RPT; ++i) {
                const float xv = xs[r0 + i * RS][f];
                accA[i] = fmaf(xv, wd, accA[i]);
                accB[i] = fmaf(xv, wb, accB[i]);
            }
        }
        const float bo = bias[o];
#pragma unroll
        for (int i = 0; i < RPT; ++i) {
            const size_t row = (size_t)(n0 + r0 + i * RS);
            A[row * FO + o]  = accA[i] + bo;
            Bm[row * FO + o] = accB[i];
        }
        return;
    }

    // ==================== kNN path (R17 body, verbatim) ====================
    const int lane  = tid & 63;
    const int wave  = tid >> 6;            // 0..3
    const int bid   = blockIdx.x;
    const int cloud = (bid & 7) + 8 * (bid >> 11);
    const int pl0   = ((bid >> 3) & 255) * RPB;

    const float* xc = x + (size_t)cloud * PPTS * F;
    for (int i = tid; i < RPB * F; i += 256)
        xp[i / F][i % F] = xc[(size_t)(pl0 + i / F) * F + (i % F)];
    __syncthreads();
    if (tid < RPB) {
        float s = 0.f;
        for (int f = 0; f < F; ++f) { const float v = xp[tid][f]; s = fmaf(v, v, s); }
        rn[tid] = s;
    }
    __syncthreads();

    const float* xTc = xT + (size_t)cloud * F * PPTS;
    const float4 qv = *reinterpret_cast<const float4*>(&qn[cloud * PPTS + 4 * tid]);

    float acc[RPB][4];
#pragma unroll
    for (int r = 0; r < RPB; ++r)
#pragma unroll
        for (int c = 0; c < 4; ++c) acc[r][c] = 0.f;

    if constexpr (F % 4 == 0) {
#pragma unroll 2
        for (int f4 = 0; f4 < F / 4; ++f4) {
            float4 vf[4];
#pragma unroll
            for (int j = 0; j < 4; ++j)
                vf[j] = *reinterpret_cast<const float4*>(&xTc[(size_t)(4 * f4 + j) * PPTS + 4 * tid]);
            float4 xr[RPB];
#pragma unroll
            for (int r = 0; r < RPB; ++r) xr[r] = *reinterpret_cast<const float4*>(&xp[r][4 * f4]);
#pragma unroll
            for (int r = 0; r < RPB; ++r) {
                acc[r][0] = fmaf(vf[0].x, xr[r].x, acc[r][0]);
                acc[r][1] = fmaf(vf[0].y, xr[r].x, acc[r][1]);
                acc[r][2] = fmaf(vf[0].z, xr[r].x, acc[r][2]);
                acc[r][3] = fmaf(vf[0].w, xr[r].x, acc[r][3]);
                acc[r][0] = fmaf(vf[1].x, xr[r].y, acc[r][0]);
                acc[r][1] = fmaf(vf[1].y, xr[r].y, acc[r][1]);
                acc[r][2] = fmaf(vf[1].z, xr[r].y, acc[r][2]);
                acc[r][3] = fmaf(vf[1].w, xr[r].y, acc[r][3]);
                acc[r][0] = fmaf(vf[2].x, xr[r].z, acc[r][0]);
                acc[r][1] = fmaf(vf[2].y, xr[r].z, acc[r][1]);
                acc[r][2] = fmaf(vf[2].z, xr[r].z, acc[r][2]);
                acc[r][3] = fmaf(vf[2].w, xr[r].z, acc[r][3]);
                acc[r][0] = fmaf(vf[3].x, xr[r].w, acc[r][0]);
                acc[r][1] = fmaf(vf[3].y, xr[r].w, acc[r][1]);
                acc[r][2] = fmaf(vf[3].z, xr[r].w, acc[r][2]);
                acc[r][3] = fmaf(vf[3].w, xr[r].w, acc[r][3]);
            }
        }
    } else {
        for (int f = 0; f < F; ++f) {
            const float4 v = *reinterpret_cast<const float4*>(&xTc[(size_t)f * PPTS + 4 * tid]);
#pragma unroll
            for (int r = 0; r < RPB; ++r) {
                const float xv = xp[r][f];
                acc[r][0] = fmaf(v.x, xv, acc[r][0]);
                acc[r][1] = fmaf(v.y, xv, acc[r][1]);
                acc[r][2] = fmaf(v.z, xv, acc[r][2]);
                acc[r][3] = fmaf(v.w, xv, acc[r][3]);
            }
        }
    }
#pragma unroll
    for (int r = 0; r < RPB; ++r) {
        uint4 wv;
        float d2;
        d2 = fmaxf(rn[r] + qv.x - 2.f * acc[r][0], 0.f);
        wv.x = (4 * tid + 0 == pl0 + r) ? SELFM : __float_as_uint(d2);
        d2 = fmaxf(rn[r] + qv.y - 2.f * acc[r][1], 0.f);
        wv.y = (4 * tid + 1 == pl0 + r) ? SELFM : __float_as_uint(d2);
        d2 = fmaxf(rn[r] + qv.z - 2.f * acc[r][2], 0.f);
        wv.z = (4 * tid + 2 == pl0 + r) ? SELFM : __float_as_uint(d2);
        d2 = fmaxf(rn[r] + qv.w - 2.f * acc[r][3], 0.f);
        wv.w = (4 * tid + 3 == pl0 + r) ? SELFM : __float_as_uint(d2);
        *reinterpret_cast<uint4*>(&dmat[r][4 * tid]) = wv;
    }
    __syncthreads();

    unsigned* hw = hist[wave];
    const int r = wave;
    unsigned bits[16];
#pragma unroll
    for (int i = 0; i < 16; ++i) bits[i] = dmat[r][lane + i * 64];

    unsigned m = bits[0];
#pragma unroll
    for (int i = 1; i < 16; ++i) m = min(m, bits[i]);
    unsigned gmin = m;
    unsigned tmax = (lane < 32) ? m : 0u;
#pragma unroll
    for (int off = 1; off < 64; off <<= 1) {
        gmin = min(gmin, (unsigned)__shfl_xor((int)gmin, off));
        tmax = max(tmax, (unsigned)__shfl_xor((int)tmax, off));
    }

    unsigned sm = 0u, nam = 0xFFFFu;
    int R = KNB;
    unsigned base = gmin;
    int shift = 0;
    bool do_hist = tmax > gmin;
    if (do_hist) {
        const unsigned span = tmax - gmin;
        const int lg = 31 - __clz(span);
        shift = lg > 7 ? lg - 7 : 0;
    }

#pragma unroll 1
    for (int pass = 0; pass < 2 && do_hist; ++pass) {
        int bin[16];
#pragma unroll
        for (int j = 0; j < 5; ++j) { const int k2 = lane + j * 64; if (k2 < HPADW) hw[k2] = 0u; }
#pragma unroll
        for (int i = 0; i < 16; ++i) {
            if ((nam >> i) & 1) {
                const unsigned d = bits[i] - base;
                int b = (int)(d >> shift);
                b = b > 255 ? 255 : b;
                bin[i] = b;
                atomicAdd(&hw[hidx(b)], 1u);
            } else bin[i] = 256;
        }
        unsigned h[4];
        int cnt = 0;
#pragma unroll
        for (int j = 0; j < 4; ++j) { h[j] = hw[hidx(lane * 4 + j)]; cnt += (int)h[j]; }
        int inc = cnt;
#pragma unroll
        for (int off = 1; off < 64; off <<= 1) {
            const int nv = __shfl_up(inc, off);
            if (lane >= off) inc += nv;
        }
        const int pre = inc - cnt;
        const bool found = (pre < R && R <= inc);
        unsigned pk = 0;
        if (found) {
            int c = pre, bb = -1, cb = 0; unsigned hbv = 0;
#pragma unroll
            for (int j = 0; j < 4; ++j) {
                if (bb < 0) {
                    if (c + (int)h[j] >= R) { bb = lane * 4 + j; hbv = h[j]; cb = c; }
                    else c += (int)h[j];
                }
            }
            pk = (unsigned)bb | ((unsigned)cb << 8) | (hbv << 16);
        }
        const unsigned long long fm = __ballot(found);
        pk = (unsigned)__shfl((int)pk, __ffsll(fm) - 1);
        const int bbin = (int)(pk & 255u);
        const int cb   = (int)((pk >> 8) & 255u);
        const int hb   = (int)(pk >> 16);
        const int need = R - cb;
        unsigned nnam = 0u;
#pragma unroll
        for (int i = 0; i < 16; ++i) {
            if (bin[i] < bbin) sm |= 1u << i;
            else if (bin[i] == bbin) nnam |= 1u << i;
        }
        if (hb == need && bbin != 255) {
            sm |= nnam; R = 0; do_hist = false;
        } else {
            nam = nnam; R = need;
            if (R <= 4 || shift == 0) do_hist = false;
            else {
                base += (unsigned)bbin << shift;
                shift = shift > 8 ? shift - 8 : 0;
            }
        }
    }

#pragma unroll 1
    while (R > 0) {
        unsigned lmin = 0xFFFFFFFFu;
#pragma unroll
        for (int i = 0; i < 16; ++i)
            if ((nam >> i) & 1) lmin = min(lmin, bits[i]);
        unsigned vmin = lmin;
#pragma unroll
        for (int off = 1; off < 64; off <<= 1)
            vmin = min(vmin, (unsigned)__shfl_xor((int)vmin, off));
        unsigned eq = 0u;
#pragma unroll
        for (int i = 0; i < 16; ++i)
            if (((nam >> i) & 1) && bits[i] == vmin) eq |= 1u << i;
        int tot = __popc(eq);
#pragma unroll
        for (int off = 1; off < 64; off <<= 1) tot += __shfl_xor(tot, off);
        if (tot <= R) { sm |= eq; nam &= ~eq; R -= tot; }
        else {
#pragma unroll
            for (int i = 0; i < 16; ++i) {
                if (R > 0) {
                    const bool c2 = (eq >> i) & 1;
                    const unsigned long long mb = __ballot(c2);
                    const int t2 = (int)__popcll(mb);
                    if (t2 <= R) { if (c2) sm |= 1u << i; R -= t2; }
                    else {
                        const unsigned long long lower = mb & ((1ull << lane) - 1ull);
                        if (c2 && (int)__popcll(lower) < R) sm |= 1u << i;
                        R = 0;
                    }
                }
            }
        }
    }

    int* out = nbr + (size_t)(cloud * PPTS + pl0 + r) * KNB;
    int tot = 0;
#pragma unroll
    for (int i = 0; i < 16; ++i) {
        const bool c2 = (sm >> i) & 1;
        const unsigned long long mb = __ballot(c2);
        if (c2) {
            const int slot = tot + (int)__popcll(mb & ((1ull << lane) - 1ull));
            if (slot < KNB) out[slot] = cloud * PPTS + lane + i * 64;
        }
        tot += (int)__popcll(mb);
    }
    if (lane == 0)
        for (int s = tot; s < KNB; ++s) out[s] = cloud * PPTS + pl0 + r;
}

// ---------------------------------------------------------------------------
// Combine (float4 + XCD swizzle): x_out = relu(A + max_k Bm[nbr])
// ---------------------------------------------------------------------------
template<int FO>
__global__ __launch_bounds__(256) void combine_kernel(const float* __restrict__ A,
                                                      const float* __restrict__ Bm,
                                                      const int* __restrict__ nbr,
                                                      float* __restrict__ xout) {
    constexpr int FO4 = FO / 4;
    const int bid = (int)((blockIdx.x & 7) * (gridDim.x >> 3) + (blockIdx.x >> 3));
    const int idx = bid * 256 + threadIdx.x;
    const int n  = idx / FO4;
    const int o4 = idx % FO4;
    const int* nb = nbr + (size_t)n * KNB;
    const float4* B4 = reinterpret_cast<const float4*>(Bm);
    float4 mx = make_float4(-FLT_MAX, -FLT_MAX, -FLT_MAX, -FLT_MAX);
#pragma unroll 8
    for (int k = 0; k < KNB; ++k) {
        const float4 v = B4[(size_t)nb[k] * FO4 + o4];
        mx.x = fmaxf(mx.x, v.x); mx.y = fmaxf(mx.y, v.y);
        mx.z = fmaxf(mx.z, v.z); mx.w = fmaxf(mx.w, v.w);
    }
    const float4 a = reinterpret_cast<const float4*>(A)[idx];
    float4 rr;
    rr.x = fmaxf(a.x + mx.x, 0.f);
    rr.y = fmaxf(a.y + mx.y, 0.f);
    rr.z = fmaxf(a.z + mx.z, 0.f);
    rr.w = fmaxf(a.w + mx.w, 0.f);
    reinterpret_cast<float4*>(xout)[idx] = rr;
}

// ---------------------------------------------------------------------------
// Classifier GEMM (R15-proven): logits = X @ Wc + bc, 320 threads/block.
// ---------------------------------------------------------------------------
__global__ __launch_bounds__(320) void cls_gemm_kernel(const float* __restrict__ x,
                                                       const float* __restrict__ Wc,
                                                       const float* __restrict__ bc,
                                                       float* __restrict__ logits) {
    constexpr int RT = 16;
    __shared__ float xs[RT][256];
    __shared__ float wsm[256][NCLS];
    const int tid = threadIdx.x;
    const int n0  = blockIdx.x * RT;

    const float4* xsrc = reinterpret_cast<const float4*>(x + (size_t)n0 * 256);
    float4* xdst = reinterpret_cast<float4*>(&xs[0][0]);
    for (int i = tid; i < RT * 256 / 4; i += 320) xdst[i] = xsrc[i];
    for (int i = tid; i < 256 * NCLS; i += 320) wsm[i / NCLS][i % NCLS] = Wc[i];
    __syncthreads();

    const int o  = tid % NCLS;
    const int rg = tid / NCLS;
    float acc0 = 0.f, acc1 = 0.f;
#pragma unroll 4
    for (int f4 = 0; f4 < 64; ++f4) {
        float wv0 = wsm[4 * f4 + 0][o];
        float wv1 = wsm[4 * f4 + 1][o];
        float wv2 = wsm[4 * f4 + 2][o];
        float wv3 = wsm[4 * f4 + 3][o];
        const float4 xa = *reinterpret_cast<const float4*>(&xs[rg][4 * f4]);
        const float4 xb = *reinterpret_cast<const float4*>(&xs[rg + 8][4 * f4]);
        acc0 = fmaf(xa.x, wv0, acc0); acc0 = fmaf(xa.y, wv1, acc0);
        acc0 = fmaf(xa.z, wv2, acc0); acc0 = fmaf(xa.w, wv3, acc0);
        acc1 = fmaf(xb.x, wv0, acc1); acc1 = fmaf(xb.y, wv1, acc1);
        acc1 = fmaf(xb.z, wv2, acc1); acc1 = fmaf(xb.w, wv3, acc1);
    }
    const float bo = bc[o];
    logits[(size_t)(n0 + rg) * NCLS + o]     = acc0 + bo;
    logits[(size_t)(n0 + rg + 8) * NCLS + o] = acc1 + bo;
}

// ---------------------------------------------------------------------------
// Softmax + per-row loss
// ---------------------------------------------------------------------------
__global__ __launch_bounds__(256) void softmax_loss_kernel(const float* __restrict__ logits,
                                                           const int* __restrict__ target,
                                                           float* __restrict__ probs,
                                                           float* __restrict__ lossbuf) {
    const int tid = threadIdx.x;
    const int lane = tid & 63;
    const int n = blockIdx.x * 4 + (tid >> 6);
    float logit = -FLT_MAX;
    if (lane < NCLS) logit = logits[(size_t)n * NCLS + lane];
    float m = logit;
#pragma unroll
    for (int off = 32; off; off >>= 1) m = fmaxf(m, __shfl_xor(m, off));
    const float e = (lane < NCLS) ? __expf(logit - m) : 0.f;
    float s = e;
#pragma unroll
    for (int off = 32; off; off >>= 1) s += __shfl_xor(s, off);
    if (lane < NCLS) probs[(size_t)n * NCLS + lane] = e / s;
    const float lt = __shfl(logit, target[n]);
    if (lane == 0) lossbuf[n] = logf(s) - (lt - m);
}

__global__ __launch_bounds__(256) void loss_reduce_kernel(const float* __restrict__ lossbuf,
                                                          float* __restrict__ out) {
    __shared__ float s[256];
    float acc = 0.f;
    for (int i = threadIdx.x; i < NPTS; i += 256) acc += lossbuf[i];
    s[threadIdx.x] = acc;
    __syncthreads();
    for (int off = 128; off; off >>= 1) {
        if (threadIdx.x < off) s[threadIdx.x] += s[threadIdx.x + off];
        __syncthreads();
    }
    if (threadIdx.x == 0) out[0] = s[0] / (float)NPTS;
}

extern "C" void kernel_launch(void* const* d_in, const int* in_sizes, int n_in,
                              void* d_out, int out_size, void* d_ws, size_t ws_size,
                              hipStream_t stream) {
    (void)in_sizes; (void)n_in; (void)out_size; (void)ws_size;
    const float* x_in   = (const float*)d_in[0];
    const int*   target = (const int*)d_in[2];
    const float* W1 = (const float*)d_in[3];
    const float* b1 = (const float*)d_in[4];
    const float* W2 = (const float*)d_in[5];
    const float* b2 = (const float*)d_in[6];
    const float* W3 = (const float*)d_in[7];
    const float* b3 = (const float*)d_in[8];
    const float* Wc = (const float*)d_in[9];
    const float* bc = (const float*)d_in[10];

    // proven-safe window [0, 50MB+64KB):
    //   X [0,8M live during kNN; up to 16M after final combine)
    //   xT [8,16M)  — live features <=8MB, so disjoint from live X each layer
    //   A [16,32M) | Bm [32,48M)  — now written CONCURRENTLY with kNN (fused),
    //                               xT moved out of Bm's region to [8,16M)
    //   nbr [48,50M) | qn==lossbuf slot [50M,+64K) (disjoint lifetimes)
    //   logits [16M,+2.6M) alias dead-A during classifier phase
    char* ws = (char*)d_ws;
    float* X       = (float*)(ws);
    float* xT      = (float*)(ws + (size_t)8  * 1024 * 1024);
    float* A       = (float*)(ws + (size_t)16 * 1024 * 1024);
    float* Bm      = (float*)(ws + (size_t)32 * 1024 * 1024);
    int*   nbr     = (int*)  (ws + (size_t)48 * 1024 * 1024);
    float* lossbuf = (float*)(ws + (size_t)50 * 1024 * 1024);
    float* qn      = lossbuf;   // shared 64KB slot, disjoint lifetimes
    float* logits  = (float*)(ws + (size_t)16 * 1024 * 1024);

    float* outF  = (float*)d_out;
    float* probs = outF + 1;

    // ---- layer 1 (3 -> 64) ----
    xpose_kernel<3><<<NPTS / 256, 256, 0, stream>>>(x_in, xT, qn);
    knn_edge_kernel<3, 64><<<KNNBLK + EDGEBLK, 256, 0, stream>>>(x_in, xT, qn, nbr, W1, b1, A, Bm);
    combine_kernel<64><<<NPTS * 16 / 256, 256, 0, stream>>>(A, Bm, nbr, X);

    // ---- layer 2 (64 -> 128) ----
    xpose_kernel<64><<<NPTS / 256, 256, 0, stream>>>(X, xT, qn);
    knn_edge_kernel<64, 128><<<KNNBLK + EDGEBLK, 256, 0, stream>>>(X, xT, qn, nbr, W2, b2, A, Bm);
    combine_kernel<128><<<NPTS * 32 / 256, 256, 0, stream>>>(A, Bm, nbr, X);

    // ---- layer 3 (128 -> 256) ----
    xpose_kernel<128><<<NPTS / 256, 256, 0, stream>>>(X, xT, qn);
    knn_edge_kernel<128, 256><<<KNNBLK + EDGEBLK, 256, 0, stream>>>(X, xT, qn, nbr, W3, b3, A, Bm);
    combine_kernel<256><<<NPTS * 64 / 256, 256, 0, stream>>>(A, Bm, nbr, X);

    // ---- classifier + loss ----
    cls_gemm_kernel<<<NPTS / 16, 320, 0, stream>>>(X, Wc, bc, logits);
    softmax_loss_kernel<<<NPTS / 4, 256, 0, stream>>>(logits, target, probs, lossbuf);
    loss_reduce_kernel<<<1, 256, 0, stream>>>(lossbuf, outF);
}

// Round 19
// 332.989 us; speedup vs baseline: 1.1546x; 1.0366x over previous
//
#include <hip/hip_runtime.h>
#include <float.h>
#include <math.h>

#define BCLOUDS 16
#define PPTS    1024
#define NPTS    (BCLOUDS * PPTS)
#define KNB     32
#define NCLS    40
#define RPB     4                  // rows per knn block (= waves per block)
#define KNNBLK  (NPTS / RPB)       // 4096 knn blocks
#define EDGEBLK (NPTS / 16)        // 1024 edge blocks
#define HWORDS  128                // 256 bins, u16-packed (2/word)
#define WPADW   (HWORDS + HWORDS / 16)
#define SELFM   0xFFFFFFFFu        // self marker: above every real distance bit pattern

__device__ __forceinline__ int widx(int w) { return w + (w >> 4); }

// ---------------------------------------------------------------------------
// Transpose + norms: xT[cloud][f][p] = x[cloud*1024+p][f]; qn[p] = |x_p|^2
// ---------------------------------------------------------------------------
template<int F>
__global__ __launch_bounds__(256) void xpose_kernel(const float* __restrict__ x,
                                                    float* __restrict__ xT,
                                                    float* __restrict__ qn) {
    const int p = blockIdx.x * 256 + threadIdx.x;
    const int cloud = p >> 10, pl = p & 1023;
    const float* xr = x + (size_t)p * F;
    float* xTc = xT + (size_t)cloud * F * PPTS;
    float s = 0.f;
    for (int f = 0; f < F; ++f) {
        const float v = xr[f];
        s = fmaf(v, v, s);
        xTc[(size_t)f * PPTS + pl] = v;
    }
    qn[p] = s;
}

// ---------------------------------------------------------------------------
// FUSED kNN + edge-GEMM. kNN selection rebuilt to DRAIN THE LDS PIPE
// (the measured invariant: ~1850cy/row of LDS-pipe traffic, R12-R17):
//  - ballot/popc prefix scan + readlane broadcasts (SALU) replace
//    ds_permute shuffles for scan/broadcast
//  - binning predicated on bits <= T (~96 active lanes vs 1024)
//  - b128 dmat reads (4 vs 16) via q = 4*lane + (i&3) + 256*(i>>2)
//  - u16-packed histogram (zero 3 instr, read 2)
// Exactness: T = max of lower-32 lane minima >= 32nd smallest (32 distinct
// candidates <= T); actives never clamp (span = T-gmin); self > T excluded;
// tie paths pick globally-smallest q iteratively (matches lax.top_k).
// ---------------------------------------------------------------------------
template<int F, int FO>
__global__ __launch_bounds__(256, 2) void knn_edge_kernel(const float* __restrict__ x,
                                                          const float* __restrict__ xT,
                                                          const float* __restrict__ qn,
                                                          int* __restrict__ nbr,
                                                          const float* __restrict__ W,
                                                          const float* __restrict__ bias,
                                                          float* __restrict__ A,
                                                          float* __restrict__ Bm) {
    __shared__ unsigned dmat[RPB][PPTS];     // 16 KB
    __shared__ float    xp[RPB][F];
    __shared__ float    rn[RPB];
    __shared__ unsigned histw[RPB][WPADW];   // 2.2 KB
    __shared__ float    xs[16][F];           // edge path

    const int tid = threadIdx.x;

    if (blockIdx.x >= KNNBLK) {
        // ================= edge GEMM path (R18 body, verbatim) =================
        constexpr int RT  = 16;
        constexpr int RS  = 256 / FO;
        constexpr int RPT = RT / RS;
        const int n0 = (int)(blockIdx.x - KNNBLK) * RT;
        for (int i = tid; i < RT * F; i += 256)
            xs[i / F][i % F] = x[(size_t)n0 * F + i];
        __syncthreads();

        const int o  = tid % FO;
        const int r0 = tid / FO;
        float accA[RPT], accB[RPT];
#pragma unroll
        for (int i = 0; i < RPT; ++i) { accA[i] = 0.f; accB[i] = 0.f; }

        for (int f = 0; f < F; ++f) {
            const float wt = W[(size_t)f * FO + o];
            const float wb = W[(size_t)(F + f) * FO + o];
            const float wd = wt - wb;
#pragma unroll
            for (int i = 0; i < RPT; ++i) {
                const float xv = xs[r0 + i * RS][f];
                accA[i] = fmaf(xv, wd, accA[i]);
                accB[i] = fmaf(xv, wb, accB[i]);
            }
        }
        const float bo = bias[o];
#pragma unroll
        for (int i = 0; i < RPT; ++i) {
            const size_t row = (size_t)(n0 + r0 + i * RS);
            A[row * FO + o]  = accA[i] + bo;
            Bm[row * FO + o] = accB[i];
        }
        return;
    }

    // ==================== kNN path ====================
    const int lane  = tid & 63;
    const int wave  = tid >> 6;            // 0..3
    const int bid   = blockIdx.x;
    const int cloud = (bid & 7) + 8 * (bid >> 11);
    const int pl0   = ((bid >> 3) & 255) * RPB;

    const float* xc = x + (size_t)cloud * PPTS * F;
    for (int i = tid; i < RPB * F; i += 256)
        xp[i / F][i % F] = xc[(size_t)(pl0 + i / F) * F + (i % F)];
    __syncthreads();
    if (tid < RPB) {
        float s = 0.f;
        for (int f = 0; f < F; ++f) { const float v = xp[tid][f]; s = fmaf(v, v, s); }
        rn[tid] = s;
    }
    __syncthreads();

    const float* xTc = xT + (size_t)cloud * F * PPTS;
    const float4 qv = *reinterpret_cast<const float4*>(&qn[cloud * PPTS + 4 * tid]);

    float acc[RPB][4];
#pragma unroll
    for (int r = 0; r < RPB; ++r)
#pragma unroll
        for (int c = 0; c < 4; ++c) acc[r][c] = 0.f;

    if constexpr (F % 4 == 0) {
#pragma unroll 2
        for (int f4 = 0; f4 < F / 4; ++f4) {
            float4 vf[4];
#pragma unroll
            for (int j = 0; j < 4; ++j)
                vf[j] = *reinterpret_cast<const float4*>(&xTc[(size_t)(4 * f4 + j) * PPTS + 4 * tid]);
            float4 xr[RPB];
#pragma unroll
            for (int r = 0; r < RPB; ++r) xr[r] = *reinterpret_cast<const float4*>(&xp[r][4 * f4]);
#pragma unroll
            for (int r = 0; r < RPB; ++r) {
                acc[r][0] = fmaf(vf[0].x, xr[r].x, acc[r][0]);
                acc[r][1] = fmaf(vf[0].y, xr[r].x, acc[r][1]);
                acc[r][2] = fmaf(vf[0].z, xr[r].x, acc[r][2]);
                acc[r][3] = fmaf(vf[0].w, xr[r].x, acc[r][3]);
                acc[r][0] = fmaf(vf[1].x, xr[r].y, acc[r][0]);
                acc[r][1] = fmaf(vf[1].y, xr[r].y, acc[r][1]);
                acc[r][2] = fmaf(vf[1].z, xr[r].y, acc[r][2]);
                acc[r][3] = fmaf(vf[1].w, xr[r].y, acc[r][3]);
                acc[r][0] = fmaf(vf[2].x, xr[r].z, acc[r][0]);
                acc[r][1] = fmaf(vf[2].y, xr[r].z, acc[r][1]);
                acc[r][2] = fmaf(vf[2].z, xr[r].z, acc[r][2]);
                acc[r][3] = fmaf(vf[2].w, xr[r].z, acc[r][3]);
                acc[r][0] = fmaf(vf[3].x, xr[r].w, acc[r][0]);
                acc[r][1] = fmaf(vf[3].y, xr[r].w, acc[r][1]);
                acc[r][2] = fmaf(vf[3].z, xr[r].w, acc[r][2]);
                acc[r][3] = fmaf(vf[3].w, xr[r].w, acc[r][3]);
            }
        }
    } else {
        for (int f = 0; f < F; ++f) {
            const float4 v = *reinterpret_cast<const float4*>(&xTc[(size_t)f * PPTS + 4 * tid]);
#pragma unroll
            for (int r = 0; r < RPB; ++r) {
                const float xv = xp[r][f];
                acc[r][0] = fmaf(v.x, xv, acc[r][0]);
                acc[r][1] = fmaf(v.y, xv, acc[r][1]);
                acc[r][2] = fmaf(v.z, xv, acc[r][2]);
                acc[r][3] = fmaf(v.w, xv, acc[r][3]);
            }
        }
    }
#pragma unroll
    for (int r = 0; r < RPB; ++r) {
        uint4 wv;
        float d2;
        d2 = fmaxf(rn[r] + qv.x - 2.f * acc[r][0], 0.f);
        wv.x = (4 * tid + 0 == pl0 + r) ? SELFM : __float_as_uint(d2);
        d2 = fmaxf(rn[r] + qv.y - 2.f * acc[r][1], 0.f);
        wv.y = (4 * tid + 1 == pl0 + r) ? SELFM : __float_as_uint(d2);
        d2 = fmaxf(rn[r] + qv.z - 2.f * acc[r][2], 0.f);
        wv.z = (4 * tid + 2 == pl0 + r) ? SELFM : __float_as_uint(d2);
        d2 = fmaxf(rn[r] + qv.w - 2.f * acc[r][3], 0.f);
        wv.w = (4 * tid + 3 == pl0 + r) ? SELFM : __float_as_uint(d2);
        *reinterpret_cast<uint4*>(&dmat[r][4 * tid]) = wv;
    }
    __syncthreads();

    // ---- selection: wave w handles row w; slot i <-> q = 4*lane+(i&3)+256*(i>>2)
    unsigned* hw = histw[wave];
    const int r = wave;
    const unsigned long long lmask = (1ull << lane) - 1ull;
    unsigned bits[16];
#pragma unroll
    for (int c = 0; c < 4; ++c) {
        const uint4 bv = *reinterpret_cast<const uint4*>(&dmat[r][4 * lane + 256 * c]);
        bits[4 * c + 0] = bv.x; bits[4 * c + 1] = bv.y;
        bits[4 * c + 2] = bv.z; bits[4 * c + 3] = bv.w;
    }

    unsigned m = bits[0];
#pragma unroll
    for (int i = 1; i < 16; ++i) m = min(m, bits[i]);
    unsigned gmin = m;
    unsigned tmax = (lane < 32) ? m : 0u;
#pragma unroll
    for (int off = 1; off < 64; off <<= 1) {
        gmin = min(gmin, (unsigned)__shfl_xor((int)gmin, off));
        tmax = max(tmax, (unsigned)__shfl_xor((int)tmax, off));
    }

    // active mask: candidates <= T (>= 32 of them; self > T always)
    unsigned am = 0u;
#pragma unroll
    for (int i = 0; i < 16; ++i) am |= (bits[i] <= tmax) ? (1u << i) : 0u;

    unsigned sm = 0u, nam = am;
    int R = KNB;
    unsigned base = gmin;
    int shift = 0;
    bool do_hist = tmax > gmin;
    if (do_hist) {
        const unsigned span = tmax - gmin;
        const int lg = 31 - __clz(span);
        shift = lg > 7 ? lg - 7 : 0;       // actives land in bins <=255, no clamp
    }

#pragma unroll 1
    for (int pass = 0; pass < 2 && do_hist; ++pass) {
        int bin[16];
        // zero u16-packed hist (3 thin instrs)
#pragma unroll
        for (int j = 0; j < 3; ++j) { const int k2 = lane + j * 64; if (k2 < WPADW) hw[k2] = 0u; }
        // bin ONLY actives (sparse lanes -> thin LDS atomics)
#pragma unroll
        for (int i = 0; i < 16; ++i) {
            if ((nam >> i) & 1) {
                int b = (int)((bits[i] - base) >> shift);
                b = b > 255 ? 255 : b;     // defensive
                bin[i] = b;
                atomicAdd(&hw[widx(b >> 1)], 1u << ((b & 1) << 4));
            } else bin[i] = 256;
        }
        // read 2 packed words -> 4 bins
        const unsigned w0 = hw[widx(2 * lane)];
        const unsigned w1 = hw[widx(2 * lane + 1)];
        unsigned h[4];
        h[0] = w0 & 0xFFFFu; h[1] = w0 >> 16;
        h[2] = w1 & 0xFFFFu; h[3] = w1 >> 16;
        const int cnt = (int)(h[0] + h[1] + h[2] + h[3]);
        // ballot-based exclusive prefix (SALU, no LDS)
        int pre = 0;
#pragma unroll
        for (int b = 0; b < 11; ++b) {
            const unsigned long long mk = __ballot((cnt >> b) & 1);
            pre += (int)__popcll(mk & lmask) << b;
        }
        const int inc = pre + cnt;
        const bool found = (pre < R && R <= inc);     // exactly one lane
        unsigned pk = 0;
        if (found) {
            int c = pre, bb = -1, cb = 0; unsigned hbv = 0;
#pragma unroll
            for (int j = 0; j < 4; ++j) {
                if (bb < 0) {
                    if (c + (int)h[j] >= R) { bb = lane * 4 + j; hbv = h[j]; cb = c; }
                    else c += (int)h[j];
                }
            }
            pk = (unsigned)bb | ((unsigned)cb << 8) | (hbv << 16);
        }
        const unsigned long long fm = __ballot(found);
        const int srcl = (int)__ffsll(fm) - 1;
        pk = (unsigned)__builtin_amdgcn_readlane((int)pk, srcl);   // register bcast
        const int bbin = (int)(pk & 255u);
        const int cb   = (int)((pk >> 8) & 255u);
        const int hb   = (int)(pk >> 16);
        const int need = R - cb;                      // 1..hb
        unsigned nnam = 0u;
#pragma unroll
        for (int i = 0; i < 16; ++i) {
            if (bin[i] < bbin) sm |= 1u << i;
            else if (bin[i] == bbin) nnam |= 1u << i;
        }
        if (hb == need) {                             // exact fit (no junk possible)
            sm |= nnam; R = 0; do_hist = false;
        } else {
            nam = nnam; R = need;
            if (R <= 4 || shift == 0) do_hist = false;
            else {
                base += (unsigned)bbin << shift;
                shift = shift > 8 ? shift - 8 : 0;
            }
        }
    }

    // value-group extraction: invariant wave-popcount(nam) >= R
#pragma unroll 1
    while (R > 0) {
        unsigned lmin = 0xFFFFFFFFu;
#pragma unroll
        for (int i = 0; i < 16; ++i)
            if ((nam >> i) & 1) lmin = min(lmin, bits[i]);
        unsigned vmin = lmin;
#pragma unroll
        for (int off = 1; off < 64; off <<= 1)
            vmin = min(vmin, (unsigned)__shfl_xor((int)vmin, off));
        unsigned eq = 0u;
#pragma unroll
        for (int i = 0; i < 16; ++i)
            if (((nam >> i) & 1) && bits[i] == vmin) eq |= 1u << i;
        int tot = __popc(eq);
#pragma unroll
        for (int off = 1; off < 64; off <<= 1) tot += __shfl_xor(tot, off);
        if (tot <= R) {
            sm |= eq; nam &= ~eq; R -= tot;
        } else {
            // pick R globally-smallest q among eq (exact top_k tie-break)
#pragma unroll 1
            while (R > 0) {
                int mq = 4096, ms = -1;
#pragma unroll
                for (int i = 0; i < 16; ++i)
                    if ((eq >> i) & 1) {
                        const int qi = 4 * lane + (i & 3) + 256 * (i >> 2);
                        if (qi < mq) { mq = qi; ms = i; }
                    }
                int gq = mq;
#pragma unroll
                for (int off = 1; off < 64; off <<= 1) gq = min(gq, __shfl_xor(gq, off));
                if (mq == gq && ms >= 0) { sm |= 1u << ms; eq &= ~(1u << ms); }
                --R;
            }
        }
    }

    // emit: ballot-prefix compaction (unordered slots; membership exact)
    int* out = nbr + (size_t)(cloud * PPTS + pl0 + r) * KNB;
    int tot = 0;
#pragma unroll
    for (int i = 0; i < 16; ++i) {
        const bool c2 = (sm >> i) & 1;
        const unsigned long long mb = __ballot(c2);
        if (c2) {
            const int slot = tot + (int)__popcll(mb & lmask);
            if (slot < KNB) out[slot] = cloud * PPTS + 4 * lane + (i & 3) + 256 * (i >> 2);
        }
        tot += (int)__popcll(mb);
    }
    if (lane == 0)
        for (int s = tot; s < KNB; ++s) out[s] = cloud * PPTS + pl0 + r;
}

// ---------------------------------------------------------------------------
// Combine (float4 + XCD swizzle): x_out = relu(A + max_k Bm[nbr])
// ---------------------------------------------------------------------------
template<int FO>
__global__ __launch_bounds__(256) void combine_kernel(const float* __restrict__ A,
                                                      const float* __restrict__ Bm,
                                                      const int* __restrict__ nbr,
                                                      float* __restrict__ xout) {
    constexpr int FO4 = FO / 4;
    const int bid = (int)((blockIdx.x & 7) * (gridDim.x >> 3) + (blockIdx.x >> 3));
    const int idx = bid * 256 + threadIdx.x;
    const int n  = idx / FO4;
    const int o4 = idx % FO4;
    const int* nb = nbr + (size_t)n * KNB;
    const float4* B4 = reinterpret_cast<const float4*>(Bm);
    float4 mx = make_float4(-FLT_MAX, -FLT_MAX, -FLT_MAX, -FLT_MAX);
#pragma unroll 8
    for (int k = 0; k < KNB; ++k) {
        const float4 v = B4[(size_t)nb[k] * FO4 + o4];
        mx.x = fmaxf(mx.x, v.x); mx.y = fmaxf(mx.y, v.y);
        mx.z = fmaxf(mx.z, v.z); mx.w = fmaxf(mx.w, v.w);
    }
    const float4 a = reinterpret_cast<const float4*>(A)[idx];
    float4 rr;
    rr.x = fmaxf(a.x + mx.x, 0.f);
    rr.y = fmaxf(a.y + mx.y, 0.f);
    rr.z = fmaxf(a.z + mx.z, 0.f);
    rr.w = fmaxf(a.w + mx.w, 0.f);
    reinterpret_cast<float4*>(xout)[idx] = rr;
}

// ---------------------------------------------------------------------------
// Classifier GEMM (R15-proven): logits = X @ Wc + bc, 320 threads/block.
// ---------------------------------------------------------------------------
__global__ __launch_bounds__(320) void cls_gemm_kernel(const float* __restrict__ x,
                                                       const float* __restrict__ Wc,
                                                       const float* __restrict__ bc,
                                                       float* __restrict__ logits) {
    constexpr int RT = 16;
    __shared__ float xs[RT][256];
    __shared__ float wsm[256][NCLS];
    const int tid = threadIdx.x;
    const int n0  = blockIdx.x * RT;

    const float4* xsrc = reinterpret_cast<const float4*>(x + (size_t)n0 * 256);
    float4* xdst = reinterpret_cast<float4*>(&xs[0][0]);
    for (int i = tid; i < RT * 256 / 4; i += 320) xdst[i] = xsrc[i];
    for (int i = tid; i < 256 * NCLS; i += 320) wsm[i / NCLS][i % NCLS] = Wc[i];
    __syncthreads();

    const int o  = tid % NCLS;
    const int rg = tid / NCLS;
    float acc0 = 0.f, acc1 = 0.f;
#pragma unroll 4
    for (int f4 = 0; f4 < 64; ++f4) {
        float wv0 = wsm[4 * f4 + 0][o];
        float wv1 = wsm[4 * f4 + 1][o];
        float wv2 = wsm[4 * f4 + 2][o];
        float wv3 = wsm[4 * f4 + 3][o];
        const float4 xa = *reinterpret_cast<const float4*>(&xs[rg][4 * f4]);
        const float4 xb = *reinterpret_cast<const float4*>(&xs[rg + 8][4 * f4]);
        acc0 = fmaf(xa.x, wv0, acc0); acc0 = fmaf(xa.y, wv1, acc0);
        acc0 = fmaf(xa.z, wv2, acc0); acc0 = fmaf(xa.w, wv3, acc0);
        acc1 = fmaf(xb.x, wv0, acc1); acc1 = fmaf(xb.y, wv1, acc1);
        acc1 = fmaf(xb.z, wv2, acc1); acc1 = fmaf(xb.w, wv3, acc1);
    }
    const float bo = bc[o];
    logits[(size_t)(n0 + rg) * NCLS + o]     = acc0 + bo;
    logits[(size_t)(n0 + rg + 8) * NCLS + o] = acc1 + bo;
}

// ---------------------------------------------------------------------------
// Softmax + per-row loss
// ---------------------------------------------------------------------------
__global__ __launch_bounds__(256) void softmax_loss_kernel(const float* __restrict__ logits,
                                                           const int* __restrict__ target,
                                                           float* __restrict__ probs,
                                                           float* __restrict__ lossbuf) {
    const int tid = threadIdx.x;
    const int lane = tid & 63;
    const int n = blockIdx.x * 4 + (tid >> 6);
    float logit = -FLT_MAX;
    if (lane < NCLS) logit = logits[(size_t)n * NCLS + lane];
    float m = logit;
#pragma unroll
    for (int off = 32; off; off >>= 1) m = fmaxf(m, __shfl_xor(m, off));
    const float e = (lane < NCLS) ? __expf(logit - m) : 0.f;
    float s = e;
#pragma unroll
    for (int off = 32; off; off >>= 1) s += __shfl_xor(s, off);
    if (lane < NCLS) probs[(size_t)n * NCLS + lane] = e / s;
    const float lt = __shfl(logit, target[n]);
    if (lane == 0) lossbuf[n] = logf(s) - (lt - m);
}

__global__ __launch_bounds__(256) void loss_reduce_kernel(const float* __restrict__ lossbuf,
                                                          float* __restrict__ out) {
    __shared__ float s[256];
    float acc = 0.f;
    for (int i = threadIdx.x; i < NPTS; i += 256) acc += lossbuf[i];
    s[threadIdx.x] = acc;
    __syncthreads();
    for (int off = 128; off; off >>= 1) {
        if (threadIdx.x < off) s[threadIdx.x] += s[threadIdx.x + off];
        __syncthreads();
    }
    if (threadIdx.x == 0) out[0] = s[0] / (float)NPTS;
}

extern "C" void kernel_launch(void* const* d_in, const int* in_sizes, int n_in,
                              void* d_out, int out_size, void* d_ws, size_t ws_size,
                              hipStream_t stream) {
    (void)in_sizes; (void)n_in; (void)out_size; (void)ws_size;
    const float* x_in   = (const float*)d_in[0];
    const int*   target = (const int*)d_in[2];
    const float* W1 = (const float*)d_in[3];
    const float* b1 = (const float*)d_in[4];
    const float* W2 = (const float*)d_in[5];
    const float* b2 = (const float*)d_in[6];
    const float* W3 = (const float*)d_in[7];
    const float* b3 = (const float*)d_in[8];
    const float* Wc = (const float*)d_in[9];
    const float* bc = (const float*)d_in[10];

    // proven-safe window [0, 50MB+64KB) (R18 layout):
    //   X [0,8M live during kNN; up to 16M after final combine)
    //   xT [8,16M) | A [16,32M) | Bm [32,48M) | nbr [48,50M)
    //   qn==lossbuf slot [50M,+64K) (disjoint lifetimes)
    //   logits [16M,+2.6M) alias dead-A during classifier phase
    char* ws = (char*)d_ws;
    float* X       = (float*)(ws);
    float* xT      = (float*)(ws + (size_t)8  * 1024 * 1024);
    float* A       = (float*)(ws + (size_t)16 * 1024 * 1024);
    float* Bm      = (float*)(ws + (size_t)32 * 1024 * 1024);
    int*   nbr     = (int*)  (ws + (size_t)48 * 1024 * 1024);
    float* lossbuf = (float*)(ws + (size_t)50 * 1024 * 1024);
    float* qn      = lossbuf;
    float* logits  = (float*)(ws + (size_t)16 * 1024 * 1024);

    float* outF  = (float*)d_out;
    float* probs = outF + 1;

    // ---- layer 1 (3 -> 64) ----
    xpose_kernel<3><<<NPTS / 256, 256, 0, stream>>>(x_in, xT, qn);
    knn_edge_kernel<3, 64><<<KNNBLK + EDGEBLK, 256, 0, stream>>>(x_in, xT, qn, nbr, W1, b1, A, Bm);
    combine_kernel<64><<<NPTS * 16 / 256, 256, 0, stream>>>(A, Bm, nbr, X);

    // ---- layer 2 (64 -> 128) ----
    xpose_kernel<64><<<NPTS / 256, 256, 0, stream>>>(X, xT, qn);
    knn_edge_kernel<64, 128><<<KNNBLK + EDGEBLK, 256, 0, stream>>>(X, xT, qn, nbr, W2, b2, A, Bm);
    combine_kernel<128><<<NPTS * 32 / 256, 256, 0, stream>>>(A, Bm, nbr, X);

    // ---- layer 3 (128 -> 256) ----
    xpose_kernel<128><<<NPTS / 256, 256, 0, stream>>>(X, xT, qn);
    knn_edge_kernel<128, 256><<<KNNBLK + EDGEBLK, 256, 0, stream>>>(X, xT, qn, nbr, W3, b3, A, Bm);
    combine_kernel<256><<<NPTS * 64 / 256, 256, 0, stream>>>(A, Bm, nbr, X);

    // ---- classifier + loss ----
    cls_gemm_kernel<<<NPTS / 16, 320, 0, stream>>>(X, Wc, bc, logits);
    softmax_loss_kernel<<<NPTS / 4, 256, 0, stream>>>(logits, target, probs, lossbuf);
    loss_reduce_kernel<<<1, 256, 0, stream>>>(lossbuf, outF);
}

// Round 20
// 332.517 us; speedup vs baseline: 1.1562x; 1.0014x over previous
//
#include <hip/hip_runtime.h>
#include <float.h>
#include <math.h>

#define BCLOUDS 16
#define PPTS    1024
#define NPTS    (BCLOUDS * PPTS)
#define KNB     32
#define NCLS    40
#define RPB     4                  // rows per knn block (= waves per block)
#define KNNBLK  (NPTS / RPB)       // 4096 knn blocks
#define EDGEBLK (NPTS / 16)        // 1024 edge blocks
#define NBINS   512                // bins per pass (9 bits)
#define HWORDS  (NBINS / 2)        // u16-packed words
#define WPADW   (HWORDS + HWORDS / 16)
#define SELFM   0xFFFFFFFFu        // self marker: above every real distance bit pattern

__device__ __forceinline__ int widx(int w) { return w + (w >> 4); }

// ---------------------------------------------------------------------------
// Transpose + norms: xT[cloud][f][p] = x[cloud*1024+p][f]; qn[p] = |x_p|^2
// ---------------------------------------------------------------------------
template<int F>
__global__ __launch_bounds__(256) void xpose_kernel(const float* __restrict__ x,
                                                    float* __restrict__ xT,
                                                    float* __restrict__ qn) {
    const int p = blockIdx.x * 256 + threadIdx.x;
    const int cloud = p >> 10, pl = p & 1023;
    const float* xr = x + (size_t)p * F;
    float* xTc = xT + (size_t)cloud * F * PPTS;
    float s = 0.f;
    for (int f = 0; f < F; ++f) {
        const float v = xr[f];
        s = fmaf(v, v, s);
        xTc[(size_t)f * PPTS + pl] = v;
    }
    qn[p] = s;
}

// ---------------------------------------------------------------------------
// FUSED kNN + edge-GEMM. Selection (R19 lean version + this round):
//  - 512-bin u16-packed first pass (more exact-fit exits, pass-2 rare)
//  - ballot/popc SALU prefix; readlane broadcasts
//  - O(1) exact tie-fill via ballot bitplanes in ascending-q order
//  - group-size reduce via ballot bitplanes (no ds_permute)
// Exactness: T = max of lower-32 lane minima >= 32nd smallest; actives never
// clamp; self > T excluded; tie-break = smallest q (matches lax.top_k).
// ---------------------------------------------------------------------------
template<int F, int FO>
__global__ __launch_bounds__(256, 2) void knn_edge_kernel(const float* __restrict__ x,
                                                          const float* __restrict__ xT,
                                                          const float* __restrict__ qn,
                                                          int* __restrict__ nbr,
                                                          const float* __restrict__ W,
                                                          const float* __restrict__ bias,
                                                          float* __restrict__ A,
                                                          float* __restrict__ Bm) {
    __shared__ unsigned dmat[RPB][PPTS];     // 16 KB
    __shared__ float    xp[RPB][F];
    __shared__ float    rn[RPB];
    __shared__ unsigned histw[RPB][WPADW];   // 4.4 KB
    __shared__ float    xs[16][F];           // edge path

    const int tid = threadIdx.x;

    if (blockIdx.x >= KNNBLK) {
        // ================= edge GEMM path (R18 body, verbatim) =================
        constexpr int RT  = 16;
        constexpr int RS  = 256 / FO;
        constexpr int RPT = RT / RS;
        const int n0 = (int)(blockIdx.x - KNNBLK) * RT;
        for (int i = tid; i < RT * F; i += 256)
            xs[i / F][i % F] = x[(size_t)n0 * F + i];
        __syncthreads();

        const int o  = tid % FO;
        const int r0 = tid / FO;
        float accA[RPT], accB[RPT];
#pragma unroll
        for (int i = 0; i < RPT; ++i) { accA[i] = 0.f; accB[i] = 0.f; }

        for (int f = 0; f < F; ++f) {
            const float wt = W[(size_t)f * FO + o];
            const float wb = W[(size_t)(F + f) * FO + o];
            const float wd = wt - wb;
#pragma unroll
            for (int i = 0; i < RPT; ++i) {
                const float xv = xs[r0 + i * RS][f];
                accA[i] = fmaf(xv, wd, accA[i]);
                accB[i] = fmaf(xv, wb, accB[i]);
            }
        }
        const float bo = bias[o];
#pragma unroll
        for (int i = 0; i < RPT; ++i) {
            const size_t row = (size_t)(n0 + r0 + i * RS);
            A[row * FO + o]  = accA[i] + bo;
            Bm[row * FO + o] = accB[i];
        }
        return;
    }

    // ==================== kNN path ====================
    const int lane  = tid & 63;
    const int wave  = tid >> 6;            // 0..3
    const int bid   = blockIdx.x;
    const int cloud = (bid & 7) + 8 * (bid >> 11);
    const int pl0   = ((bid >> 3) & 255) * RPB;

    const float* xc = x + (size_t)cloud * PPTS * F;
    for (int i = tid; i < RPB * F; i += 256)
        xp[i / F][i % F] = xc[(size_t)(pl0 + i / F) * F + (i % F)];
    __syncthreads();
    if (tid < RPB) {
        float s = 0.f;
        for (int f = 0; f < F; ++f) { const float v = xp[tid][f]; s = fmaf(v, v, s); }
        rn[tid] = s;
    }
    __syncthreads();

    const float* xTc = xT + (size_t)cloud * F * PPTS;
    const float4 qv = *reinterpret_cast<const float4*>(&qn[cloud * PPTS + 4 * tid]);

    float acc[RPB][4];
#pragma unroll
    for (int r = 0; r < RPB; ++r)
#pragma unroll
        for (int c = 0; c < 4; ++c) acc[r][c] = 0.f;

    if constexpr (F % 4 == 0) {
#pragma unroll 2
        for (int f4 = 0; f4 < F / 4; ++f4) {
            float4 vf[4];
#pragma unroll
            for (int j = 0; j < 4; ++j)
                vf[j] = *reinterpret_cast<const float4*>(&xTc[(size_t)(4 * f4 + j) * PPTS + 4 * tid]);
            float4 xr[RPB];
#pragma unroll
            for (int r = 0; r < RPB; ++r) xr[r] = *reinterpret_cast<const float4*>(&xp[r][4 * f4]);
#pragma unroll
            for (int r = 0; r < RPB; ++r) {
                acc[r][0] = fmaf(vf[0].x, xr[r].x, acc[r][0]);
                acc[r][1] = fmaf(vf[0].y, xr[r].x, acc[r][1]);
                acc[r][2] = fmaf(vf[0].z, xr[r].x, acc[r][2]);
                acc[r][3] = fmaf(vf[0].w, xr[r].x, acc[r][3]);
                acc[r][0] = fmaf(vf[1].x, xr[r].y, acc[r][0]);
                acc[r][1] = fmaf(vf[1].y, xr[r].y, acc[r][1]);
                acc[r][2] = fmaf(vf[1].z, xr[r].y, acc[r][2]);
                acc[r][3] = fmaf(vf[1].w, xr[r].y, acc[r][3]);
                acc[r][0] = fmaf(vf[2].x, xr[r].z, acc[r][0]);
                acc[r][1] = fmaf(vf[2].y, xr[r].z, acc[r][1]);
                acc[r][2] = fmaf(vf[2].z, xr[r].z, acc[r][2]);
                acc[r][3] = fmaf(vf[2].w, xr[r].z, acc[r][3]);
                acc[r][0] = fmaf(vf[3].x, xr[r].w, acc[r][0]);
                acc[r][1] = fmaf(vf[3].y, xr[r].w, acc[r][1]);
                acc[r][2] = fmaf(vf[3].z, xr[r].w, acc[r][2]);
                acc[r][3] = fmaf(vf[3].w, xr[r].w, acc[r][3]);
            }
        }
    } else {
        for (int f = 0; f < F; ++f) {
            const float4 v = *reinterpret_cast<const float4*>(&xTc[(size_t)f * PPTS + 4 * tid]);
#pragma unroll
            for (int r = 0; r < RPB; ++r) {
                const float xv = xp[r][f];
                acc[r][0] = fmaf(v.x, xv, acc[r][0]);
                acc[r][1] = fmaf(v.y, xv, acc[r][1]);
                acc[r][2] = fmaf(v.z, xv, acc[r][2]);
                acc[r][3] = fmaf(v.w, xv, acc[r][3]);
            }
        }
    }
#pragma unroll
    for (int r = 0; r < RPB; ++r) {
        uint4 wv;
        float d2;
        d2 = fmaxf(rn[r] + qv.x - 2.f * acc[r][0], 0.f);
        wv.x = (4 * tid + 0 == pl0 + r) ? SELFM : __float_as_uint(d2);
        d2 = fmaxf(rn[r] + qv.y - 2.f * acc[r][1], 0.f);
        wv.y = (4 * tid + 1 == pl0 + r) ? SELFM : __float_as_uint(d2);
        d2 = fmaxf(rn[r] + qv.z - 2.f * acc[r][2], 0.f);
        wv.z = (4 * tid + 2 == pl0 + r) ? SELFM : __float_as_uint(d2);
        d2 = fmaxf(rn[r] + qv.w - 2.f * acc[r][3], 0.f);
        wv.w = (4 * tid + 3 == pl0 + r) ? SELFM : __float_as_uint(d2);
        *reinterpret_cast<uint4*>(&dmat[r][4 * tid]) = wv;
    }
    __syncthreads();

    // ---- selection: wave w row w; slot i = 4c+j <-> q = 4*lane + j + 256*c
    unsigned* hw = histw[wave];
    const int r = wave;
    const unsigned long long lmask = (1ull << lane) - 1ull;
    unsigned bits[16];
#pragma unroll
    for (int c = 0; c < 4; ++c) {
        const uint4 bv = *reinterpret_cast<const uint4*>(&dmat[r][4 * lane + 256 * c]);
        bits[4 * c + 0] = bv.x; bits[4 * c + 1] = bv.y;
        bits[4 * c + 2] = bv.z; bits[4 * c + 3] = bv.w;
    }

    unsigned m = bits[0];
#pragma unroll
    for (int i = 1; i < 16; ++i) m = min(m, bits[i]);
    unsigned gmin = m;
    unsigned tmax = (lane < 32) ? m : 0u;
#pragma unroll
    for (int off = 1; off < 64; off <<= 1) {
        gmin = min(gmin, (unsigned)__shfl_xor((int)gmin, off));
        tmax = max(tmax, (unsigned)__shfl_xor((int)tmax, off));
    }

    // actives: candidates <= T (>= 32 of them; self > T)
    unsigned am = 0u;
#pragma unroll
    for (int i = 0; i < 16; ++i) am |= (bits[i] <= tmax) ? (1u << i) : 0u;

    unsigned sm = 0u, nam = am;
    int R = KNB;
    unsigned base = gmin;
    int shift = 0;
    bool do_hist = tmax > gmin;
    if (do_hist) {
        const unsigned span = tmax - gmin;
        const int lg = 31 - __clz(span);
        shift = lg > 8 ? lg - 8 : 0;       // actives land in bins <=511
    }

#pragma unroll 1
    for (int pass = 0; pass < 2 && do_hist; ++pass) {
        int bin[16];
        // zero u16-packed 512-bin hist
#pragma unroll
        for (int j = 0; j < 5; ++j) { const int k2 = lane + j * 64; if (k2 < WPADW) hw[k2] = 0u; }
        // bin ONLY actives
#pragma unroll
        for (int i = 0; i < 16; ++i) {
            if ((nam >> i) & 1) {
                int b = (int)((bits[i] - base) >> shift);
                b = b > (NBINS - 1) ? (NBINS - 1) : b;   // defensive
                bin[i] = b;
                atomicAdd(&hw[widx(b >> 1)], 1u << ((b & 1) << 4));
            } else bin[i] = NBINS;
        }
        // read 4 packed words -> 8 bins per lane
        unsigned h[8];
        int cnt = 0;
#pragma unroll
        for (int j = 0; j < 4; ++j) {
            const unsigned w = hw[widx(4 * lane + j)];
            h[2 * j]     = w & 0xFFFFu;
            h[2 * j + 1] = w >> 16;
            cnt += (int)(h[2 * j] + h[2 * j + 1]);
        }
        // ballot-based exclusive prefix (SALU)
        int pre = 0;
#pragma unroll
        for (int b = 0; b < 11; ++b) {
            const unsigned long long mk = __ballot((cnt >> b) & 1);
            pre += (int)__popcll(mk & lmask) << b;
        }
        const int inc = pre + cnt;
        const bool found = (pre < R && R <= inc);
        unsigned pk = 0;
        if (found) {
            int c = pre, bb = -1, cb = 0; unsigned hbv = 0;
#pragma unroll
            for (int j = 0; j < 8; ++j) {
                if (bb < 0) {
                    if (c + (int)h[j] >= R) { bb = lane * 8 + j; hbv = h[j]; cb = c; }
                    else c += (int)h[j];
                }
            }
            pk = (unsigned)bb | ((unsigned)cb << 9) | (hbv << 16);
        }
        const unsigned long long fm = __ballot(found);
        const int srcl = (int)__ffsll(fm) - 1;
        pk = (unsigned)__builtin_amdgcn_readlane((int)pk, srcl);
        const int bbin = (int)(pk & 511u);
        const int cb   = (int)((pk >> 9) & 127u);
        const int hb   = (int)(pk >> 16);
        const int need = R - cb;                      // 1..hb
        unsigned nnam = 0u;
#pragma unroll
        for (int i = 0; i < 16; ++i) {
            if (bin[i] < bbin) sm |= 1u << i;
            else if (bin[i] == bbin) nnam |= 1u << i;
        }
        if (hb == need) {                             // exact fit
            sm |= nnam; R = 0; do_hist = false;
        } else {
            nam = nnam; R = need;
            if (R <= 4 || shift == 0) do_hist = false;
            else {
                base += (unsigned)bbin << shift;
                shift = shift > 9 ? shift - 9 : 0;
            }
        }
    }

    // value-group extraction: invariant wave-popcount(nam) >= R
#pragma unroll 1
    while (R > 0) {
        unsigned lmin = 0xFFFFFFFFu;
#pragma unroll
        for (int i = 0; i < 16; ++i)
            if ((nam >> i) & 1) lmin = min(lmin, bits[i]);
        unsigned vmin = lmin;
#pragma unroll
        for (int off = 1; off < 64; off <<= 1)
            vmin = min(vmin, (unsigned)__shfl_xor((int)vmin, off));
        unsigned eq = 0u;
#pragma unroll
        for (int i = 0; i < 16; ++i)
            if (((nam >> i) & 1) && bits[i] == vmin) eq |= 1u << i;
        // group size via ballot bitplanes (SALU, no LDS)
        const int ec = __popc(eq);                    // 0..16
        int tot = 0;
#pragma unroll
        for (int b = 0; b < 5; ++b) {
            const unsigned long long mk = __ballot((ec >> b) & 1);
            tot += (int)__popcll(mk) << b;
        }
        if (tot <= R) {
            sm |= eq; nam &= ~eq; R -= tot;
        } else {
            // O(1) exact fill: R smallest-q among eq; q = 4*lane + j + 256*c
#pragma unroll
            for (int c = 0; c < 4; ++c) {
                if (R > 0) {
                    const unsigned nib = (eq >> (4 * c)) & 0xFu;
                    const int cn = __popc(nib);       // 0..4
                    int prel = 0, totc = 0;
#pragma unroll
                    for (int b = 0; b < 3; ++b) {
                        const unsigned long long mk = __ballot((cn >> b) & 1);
                        prel += (int)__popcll(mk & lmask) << b;
                        totc += (int)__popcll(mk) << b;
                    }
                    int take = R - prel;
                    take = take < 0 ? 0 : (take > cn ? cn : take);
#pragma unroll
                    for (int j = 0; j < 4; ++j) {
                        if (((nib >> j) & 1) && take > 0) { sm |= 1u << (4 * c + j); --take; }
                    }
                    R -= totc < R ? totc : R;
                }
            }
            R = 0;
        }
    }

    // emit: ballot-prefix compaction (unordered slots; membership exact)
    int* out = nbr + (size_t)(cloud * PPTS + pl0 + r) * KNB;
    int tot = 0;
#pragma unroll
    for (int i = 0; i < 16; ++i) {
        const bool c2 = (sm >> i) & 1;
        const unsigned long long mb = __ballot(c2);
        if (c2) {
            const int slot = tot + (int)__popcll(mb & lmask);
            if (slot < KNB) out[slot] = cloud * PPTS + 4 * lane + (i & 3) + 256 * (i >> 2);
        }
        tot += (int)__popcll(mb);
    }
    if (lane == 0)
        for (int s = tot; s < KNB; ++s) out[s] = cloud * PPTS + pl0 + r;
}

// ---------------------------------------------------------------------------
// Combine (float4 + XCD swizzle): x_out = relu(A + max_k Bm[nbr])
// ---------------------------------------------------------------------------
template<int FO>
__global__ __launch_bounds__(256) void combine_kernel(const float* __restrict__ A,
                                                      const float* __restrict__ Bm,
                                                      const int* __restrict__ nbr,
                                                      float* __restrict__ xout) {
    constexpr int FO4 = FO / 4;
    const int bid = (int)((blockIdx.x & 7) * (gridDim.x >> 3) + (blockIdx.x >> 3));
    const int idx = bid * 256 + threadIdx.x;
    const int n  = idx / FO4;
    const int o4 = idx % FO4;
    const int* nb = nbr + (size_t)n * KNB;
    const float4* B4 = reinterpret_cast<const float4*>(Bm);
    float4 mx = make_float4(-FLT_MAX, -FLT_MAX, -FLT_MAX, -FLT_MAX);
#pragma unroll 8
    for (int k = 0; k < KNB; ++k) {
        const float4 v = B4[(size_t)nb[k] * FO4 + o4];
        mx.x = fmaxf(mx.x, v.x); mx.y = fmaxf(mx.y, v.y);
        mx.z = fmaxf(mx.z, v.z); mx.w = fmaxf(mx.w, v.w);
    }
    const float4 a = reinterpret_cast<const float4*>(A)[idx];
    float4 rr;
    rr.x = fmaxf(a.x + mx.x, 0.f);
    rr.y = fmaxf(a.y + mx.y, 0.f);
    rr.z = fmaxf(a.z + mx.z, 0.f);
    rr.w = fmaxf(a.w + mx.w, 0.f);
    reinterpret_cast<float4*>(xout)[idx] = rr;
}

// ---------------------------------------------------------------------------
// Classifier GEMM (R15-proven): logits = X @ Wc + bc, 320 threads/block.
// ---------------------------------------------------------------------------
__global__ __launch_bounds__(320) void cls_gemm_kernel(const float* __restrict__ x,
                                                       const float* __restrict__ Wc,
                                                       const float* __restrict__ bc,
                                                       float* __restrict__ logits) {
    constexpr int RT = 16;
    __shared__ float xs[RT][256];
    __shared__ float wsm[256][NCLS];
    const int tid = threadIdx.x;
    const int n0  = blockIdx.x * RT;

    const float4* xsrc = reinterpret_cast<const float4*>(x + (size_t)n0 * 256);
    float4* xdst = reinterpret_cast<float4*>(&xs[0][0]);
    for (int i = tid; i < RT * 256 / 4; i += 320) xdst[i] = xsrc[i];
    for (int i = tid; i < 256 * NCLS; i += 320) wsm[i / NCLS][i % NCLS] = Wc[i];
    __syncthreads();

    const int o  = tid % NCLS;
    const int rg = tid / NCLS;
    float acc0 = 0.f, acc1 = 0.f;
#pragma unroll 4
    for (int f4 = 0; f4 < 64; ++f4) {
        float wv0 = wsm[4 * f4 + 0][o];
        float wv1 = wsm[4 * f4 + 1][o];
        float wv2 = wsm[4 * f4 + 2][o];
        float wv3 = wsm[4 * f4 + 3][o];
        const float4 xa = *reinterpret_cast<const float4*>(&xs[rg][4 * f4]);
        const float4 xb = *reinterpret_cast<const float4*>(&xs[rg + 8][4 * f4]);
        acc0 = fmaf(xa.x, wv0, acc0); acc0 = fmaf(xa.y, wv1, acc0);
        acc0 = fmaf(xa.z, wv2, acc0); acc0 = fmaf(xa.w, wv3, acc0);
        acc1 = fmaf(xb.x, wv0, acc1); acc1 = fmaf(xb.y, wv1, acc1);
        acc1 = fmaf(xb.z, wv2, acc1); acc1 = fmaf(xb.w, wv3, acc1);
    }
    const float bo = bc[o];
    logits[(size_t)(n0 + rg) * NCLS + o]     = acc0 + bo;
    logits[(size_t)(n0 + rg + 8) * NCLS + o] = acc1 + bo;
}

// ---------------------------------------------------------------------------
// Softmax + per-row loss
// ---------------------------------------------------------------------------
__global__ __launch_bounds__(256) void softmax_loss_kernel(const float* __restrict__ logits,
                                                           const int* __restrict__ target,
                                                           float* __restrict__ probs,
                                                           float* __restrict__ lossbuf) {
    const int tid = threadIdx.x;
    const int lane = tid & 63;
    const int n = blockIdx.x * 4 + (tid >> 6);
    float logit = -FLT_MAX;
    if (lane < NCLS) logit = logits[(size_t)n * NCLS + lane];
    float m = logit;
#pragma unroll
    for (int off = 32; off; off >>= 1) m = fmaxf(m, __shfl_xor(m, off));
    const float e = (lane < NCLS) ? __expf(logit - m) : 0.f;
    float s = e;
#pragma unroll
    for (int off = 32; off; off >>= 1) s += __shfl_xor(s, off);
    if (lane < NCLS) probs[(size_t)n * NCLS + lane] = e / s;
    const float lt = __shfl(logit, target[n]);
    if (lane == 0) lossbuf[n] = logf(s) - (lt - m);
}

__global__ __launch_bounds__(256) void loss_reduce_kernel(const float* __restrict__ lossbuf,
                                                          float* __restrict__ out) {
    __shared__ float s[256];
    float acc = 0.f;
    for (int i = threadIdx.x; i < NPTS; i += 256) acc += lossbuf[i];
    s[threadIdx.x] = acc;
    __syncthreads();
    for (int off = 128; off; off >>= 1) {
        if (threadIdx.x < off) s[threadIdx.x] += s[threadIdx.x + off];
        __syncthreads();
    }
    if (threadIdx.x == 0) out[0] = s[0] / (float)NPTS;
}

extern "C" void kernel_launch(void* const* d_in, const int* in_sizes, int n_in,
                              void* d_out, int out_size, void* d_ws, size_t ws_size,
                              hipStream_t stream) {
    (void)in_sizes; (void)n_in; (void)out_size; (void)ws_size;
    const float* x_in   = (const float*)d_in[0];
    const int*   target = (const int*)d_in[2];
    const float* W1 = (const float*)d_in[3];
    const float* b1 = (const float*)d_in[4];
    const float* W2 = (const float*)d_in[5];
    const float* b2 = (const float*)d_in[6];
    const float* W3 = (const float*)d_in[7];
    const float* b3 = (const float*)d_in[8];
    const float* Wc = (const float*)d_in[9];
    const float* bc = (const float*)d_in[10];

    // proven-safe window [0, 50MB+64KB) (R18/R19 layout):
    //   X [0,8M live during kNN) | xT [8,16M) | A [16,32M) | Bm [32,48M)
    //   nbr [48,50M) | qn==lossbuf [50M,+64K) | logits alias dead-A
    char* ws = (char*)d_ws;
    float* X       = (float*)(ws);
    float* xT      = (float*)(ws + (size_t)8  * 1024 * 1024);
    float* A       = (float*)(ws + (size_t)16 * 1024 * 1024);
    float* Bm      = (float*)(ws + (size_t)32 * 1024 * 1024);
    int*   nbr     = (int*)  (ws + (size_t)48 * 1024 * 1024);
    float* lossbuf = (float*)(ws + (size_t)50 * 1024 * 1024);
    float* qn      = lossbuf;
    float* logits  = (float*)(ws + (size_t)16 * 1024 * 1024);

    float* outF  = (float*)d_out;
    float* probs = outF + 1;

    // ---- layer 1 (3 -> 64) ----
    xpose_kernel<3><<<NPTS / 256, 256, 0, stream>>>(x_in, xT, qn);
    knn_edge_kernel<3, 64><<<KNNBLK + EDGEBLK, 256, 0, stream>>>(x_in, xT, qn, nbr, W1, b1, A, Bm);
    combine_kernel<64><<<NPTS * 16 / 256, 256, 0, stream>>>(A, Bm, nbr, X);

    // ---- layer 2 (64 -> 128) ----
    xpose_kernel<64><<<NPTS / 256, 256, 0, stream>>>(X, xT, qn);
    knn_edge_kernel<64, 128><<<KNNBLK + EDGEBLK, 256, 0, stream>>>(X, xT, qn, nbr, W2, b2, A, Bm);
    combine_kernel<128><<<NPTS * 32 / 256, 256, 0, stream>>>(A, Bm, nbr, X);

    // ---- layer 3 (128 -> 256) ----
    xpose_kernel<128><<<NPTS / 256, 256, 0, stream>>>(X, xT, qn);
    knn_edge_kernel<128, 256><<<KNNBLK + EDGEBLK, 256, 0, stream>>>(X, xT, qn, nbr, W3, b3, A, Bm);
    combine_kernel<256><<<NPTS * 64 / 256, 256, 0, stream>>>(A, Bm, nbr, X);

    // ---- classifier + loss ----
    cls_gemm_kernel<<<NPTS / 16, 320, 0, stream>>>(X, Wc, bc, logits);
    softmax_loss_kernel<<<NPTS / 4, 256, 0, stream>>>(logits, target, probs, lossbuf);
    loss_reduce_kernel<<<1, 256, 0, stream>>>(lossbuf, outF);
}

// Round 21
// 329.133 us; speedup vs baseline: 1.1681x; 1.0103x over previous
//
#include <hip/hip_runtime.h>
#include <float.h>
#include <math.h>

#define BCLOUDS 16
#define PPTS    1024
#define NPTS    (BCLOUDS * PPTS)
#define KNB     32
#define NCLS    40
#define RPB     4                  // rows per knn block (= waves per block)
#define KNNBLK  (NPTS / RPB)       // 4096 knn blocks
#define EDGEBLK (NPTS / 16)        // 1024 edge blocks
#define NBINS   512                // bins (9 bits), single pass
#define HWORDS  (NBINS / 2)        // u16-packed words
#define WPADW   (HWORDS + HWORDS / 16)
#define SELFM   0xFFFFFFFFu        // self marker: above every real distance bit pattern

__device__ __forceinline__ int widx(int w) { return w + (w >> 4); }

// ---------------------------------------------------------------------------
// Transpose + norms: xT[cloud][f][p] = x[cloud*1024+p][f]; qn[p] = |x_p|^2
// ---------------------------------------------------------------------------
template<int F>
__global__ __launch_bounds__(256) void xpose_kernel(const float* __restrict__ x,
                                                    float* __restrict__ xT,
                                                    float* __restrict__ qn) {
    const int p = blockIdx.x * 256 + threadIdx.x;
    const int cloud = p >> 10, pl = p & 1023;
    const float* xr = x + (size_t)p * F;
    float* xTc = xT + (size_t)cloud * F * PPTS;
    float s = 0.f;
    for (int f = 0; f < F; ++f) {
        const float v = xr[f];
        s = fmaf(v, v, s);
        xTc[(size_t)f * PPTS + pl] = v;
    }
    qn[p] = s;
}

// ---------------------------------------------------------------------------
// FUSED kNN + edge-GEMM. Selection = minimal-sweep single-pass radix:
//   sweep A: b128 loads + min chain + 2 reduces  (gmin, T)
//   sweep B: bin+atomic (actives only; no bin[] storage)
//   scan   : ballot/popc SALU prefix + boundary (readlane bcast)
//   [non-exact-fit only] nam sweep + value-group extraction (exact)
//   sweep D: fused classify+emit (predicate recomputed inline, 1 ballot/slot)
// Cost model (R20 post-mortem): time ~ sweeps x pairs; this cuts ~6+ sweeps
// to 4 in the common exact-fit case. Exactness: T = max of lower-32 lane
// minima >= 32nd smallest; actives (<=T) bin into [0,511] (no clamp/negative);
// self > T excluded; ties resolved by value-groups then smallest-q (lax.top_k).
// ---------------------------------------------------------------------------
template<int F, int FO>
__global__ __launch_bounds__(256, 2) void knn_edge_kernel(const float* __restrict__ x,
                                                          const float* __restrict__ xT,
                                                          const float* __restrict__ qn,
                                                          int* __restrict__ nbr,
                                                          const float* __restrict__ W,
                                                          const float* __restrict__ bias,
                                                          float* __restrict__ A,
                                                          float* __restrict__ Bm) {
    __shared__ unsigned dmat[RPB][PPTS];     // 16 KB
    __shared__ float    xp[RPB][F];
    __shared__ float    rn[RPB];
    __shared__ unsigned histw[RPB][WPADW];   // 4.4 KB
    __shared__ float    xs[16][F];           // edge path

    const int tid = threadIdx.x;

    if (blockIdx.x >= KNNBLK) {
        // ================= edge GEMM path (verbatim) =================
        constexpr int RT  = 16;
        constexpr int RS  = 256 / FO;
        constexpr int RPT = RT / RS;
        const int n0 = (int)(blockIdx.x - KNNBLK) * RT;
        for (int i = tid; i < RT * F; i += 256)
            xs[i / F][i % F] = x[(size_t)n0 * F + i];
        __syncthreads();

        const int o  = tid % FO;
        const int r0 = tid / FO;
        float accA[RPT], accB[RPT];
#pragma unroll
        for (int i = 0; i < RPT; ++i) { accA[i] = 0.f; accB[i] = 0.f; }

        for (int f = 0; f < F; ++f) {
            const float wt = W[(size_t)f * FO + o];
            const float wb = W[(size_t)(F + f) * FO + o];
            const float wd = wt - wb;
#pragma unroll
            for (int i = 0; i < RPT; ++i) {
                const float xv = xs[r0 + i * RS][f];
                accA[i] = fmaf(xv, wd, accA[i]);
                accB[i] = fmaf(xv, wb, accB[i]);
            }
        }
        const float bo = bias[o];
#pragma unroll
        for (int i = 0; i < RPT; ++i) {
            const size_t row = (size_t)(n0 + r0 + i * RS);
            A[row * FO + o]  = accA[i] + bo;
            Bm[row * FO + o] = accB[i];
        }
        return;
    }

    // ==================== kNN path ====================
    const int lane  = tid & 63;
    const int wave  = tid >> 6;            // 0..3
    const int bid   = blockIdx.x;
    const int cloud = (bid & 7) + 8 * (bid >> 11);
    const int pl0   = ((bid >> 3) & 255) * RPB;

    const float* xc = x + (size_t)cloud * PPTS * F;
    for (int i = tid; i < RPB * F; i += 256)
        xp[i / F][i % F] = xc[(size_t)(pl0 + i / F) * F + (i % F)];
    __syncthreads();
    if (tid < RPB) {
        float s = 0.f;
        for (int f = 0; f < F; ++f) { const float v = xp[tid][f]; s = fmaf(v, v, s); }
        rn[tid] = s;
    }
    __syncthreads();

    const float* xTc = xT + (size_t)cloud * F * PPTS;
    const float4 qv = *reinterpret_cast<const float4*>(&qn[cloud * PPTS + 4 * tid]);

    float acc[RPB][4];
#pragma unroll
    for (int r = 0; r < RPB; ++r)
#pragma unroll
        for (int c = 0; c < 4; ++c) acc[r][c] = 0.f;

    if constexpr (F % 4 == 0) {
#pragma unroll 2
        for (int f4 = 0; f4 < F / 4; ++f4) {
            float4 vf[4];
#pragma unroll
            for (int j = 0; j < 4; ++j)
                vf[j] = *reinterpret_cast<const float4*>(&xTc[(size_t)(4 * f4 + j) * PPTS + 4 * tid]);
            float4 xr[RPB];
#pragma unroll
            for (int r = 0; r < RPB; ++r) xr[r] = *reinterpret_cast<const float4*>(&xp[r][4 * f4]);
#pragma unroll
            for (int r = 0; r < RPB; ++r) {
                acc[r][0] = fmaf(vf[0].x, xr[r].x, acc[r][0]);
                acc[r][1] = fmaf(vf[0].y, xr[r].x, acc[r][1]);
                acc[r][2] = fmaf(vf[0].z, xr[r].x, acc[r][2]);
                acc[r][3] = fmaf(vf[0].w, xr[r].x, acc[r][3]);
                acc[r][0] = fmaf(vf[1].x, xr[r].y, acc[r][0]);
                acc[r][1] = fmaf(vf[1].y, xr[r].y, acc[r][1]);
                acc[r][2] = fmaf(vf[1].z, xr[r].y, acc[r][2]);
                acc[r][3] = fmaf(vf[1].w, xr[r].y, acc[r][3]);
                acc[r][0] = fmaf(vf[2].x, xr[r].z, acc[r][0]);
                acc[r][1] = fmaf(vf[2].y, xr[r].z, acc[r][1]);
                acc[r][2] = fmaf(vf[2].z, xr[r].z, acc[r][2]);
                acc[r][3] = fmaf(vf[2].w, xr[r].z, acc[r][3]);
                acc[r][0] = fmaf(vf[3].x, xr[r].w, acc[r][0]);
                acc[r][1] = fmaf(vf[3].y, xr[r].w, acc[r][1]);
                acc[r][2] = fmaf(vf[3].z, xr[r].w, acc[r][2]);
                acc[r][3] = fmaf(vf[3].w, xr[r].w, acc[r][3]);
            }
        }
    } else {
        for (int f = 0; f < F; ++f) {
            const float4 v = *reinterpret_cast<const float4*>(&xTc[(size_t)f * PPTS + 4 * tid]);
#pragma unroll
            for (int r = 0; r < RPB; ++r) {
                const float xv = xp[r][f];
                acc[r][0] = fmaf(v.x, xv, acc[r][0]);
                acc[r][1] = fmaf(v.y, xv, acc[r][1]);
                acc[r][2] = fmaf(v.z, xv, acc[r][2]);
                acc[r][3] = fmaf(v.w, xv, acc[r][3]);
            }
        }
    }
#pragma unroll
    for (int r = 0; r < RPB; ++r) {
        uint4 wv;
        float d2;
        d2 = fmaxf(rn[r] + qv.x - 2.f * acc[r][0], 0.f);
        wv.x = (4 * tid + 0 == pl0 + r) ? SELFM : __float_as_uint(d2);
        d2 = fmaxf(rn[r] + qv.y - 2.f * acc[r][1], 0.f);
        wv.y = (4 * tid + 1 == pl0 + r) ? SELFM : __float_as_uint(d2);
        d2 = fmaxf(rn[r] + qv.z - 2.f * acc[r][2], 0.f);
        wv.z = (4 * tid + 2 == pl0 + r) ? SELFM : __float_as_uint(d2);
        d2 = fmaxf(rn[r] + qv.w - 2.f * acc[r][3], 0.f);
        wv.w = (4 * tid + 3 == pl0 + r) ? SELFM : __float_as_uint(d2);
        *reinterpret_cast<uint4*>(&dmat[r][4 * tid]) = wv;
    }
    __syncthreads();

    // ---- selection: wave w row w; slot i = 4c+j <-> q = 4*lane + j + 256*c
    unsigned* hw = histw[wave];
    const int r = wave;
    const unsigned long long lmask = (1ull << lane) - 1ull;
    unsigned bits[16];
#pragma unroll
    for (int c = 0; c < 4; ++c) {
        const uint4 bv = *reinterpret_cast<const uint4*>(&dmat[r][4 * lane + 256 * c]);
        bits[4 * c + 0] = bv.x; bits[4 * c + 1] = bv.y;
        bits[4 * c + 2] = bv.z; bits[4 * c + 3] = bv.w;
    }

    // sweep A: per-lane min + reduces
    unsigned m = bits[0];
#pragma unroll
    for (int i = 1; i < 16; ++i) m = min(m, bits[i]);
    unsigned gmin = m;
    unsigned tmax = (lane < 32) ? m : 0u;
#pragma unroll
    for (int off = 1; off < 64; off <<= 1) {
        gmin = min(gmin, (unsigned)__shfl_xor((int)gmin, off));
        tmax = max(tmax, (unsigned)__shfl_xor((int)tmax, off));
    }

    unsigned sm = 0u;           // extraction-selected slots
    int bsel = -1;              // emit: select actives with bin < bsel
    int R = KNB;
    const unsigned base = gmin;
    int shift = 0;
    const bool have = tmax > gmin;
    if (have) {
        const unsigned span = tmax - gmin;
        const int lg = 31 - __clz(span);
        shift = lg > 8 ? lg - 8 : 0;       // actives -> bins [0,511]
    }

    if (have) {
        // zero u16-packed 512-bin hist
#pragma unroll
        for (int j = 0; j < 5; ++j) { const int k2 = lane + j * 64; if (k2 < WPADW) hw[k2] = 0u; }
        // sweep B: bin+atomic (actives only, bins recomputed later)
#pragma unroll
        for (int i = 0; i < 16; ++i) {
            if (bits[i] <= tmax) {
                const int b = (int)((bits[i] - base) >> shift);   // 0..511 guaranteed
                atomicAdd(&hw[widx(b >> 1)], 1u << ((b & 1) << 4));
            }
        }
        // scan: 8 bins/lane, ballot prefix
        unsigned h[8];
        int cnt = 0;
#pragma unroll
        for (int j = 0; j < 4; ++j) {
            const unsigned w = hw[widx(4 * lane + j)];
            h[2 * j]     = w & 0xFFFFu;
            h[2 * j + 1] = w >> 16;
            cnt += (int)(h[2 * j] + h[2 * j + 1]);
        }
        int pre = 0;
#pragma unroll
        for (int b = 0; b < 11; ++b) {
            const unsigned long long mk = __ballot((cnt >> b) & 1);
            pre += (int)__popcll(mk & lmask) << b;
        }
        const int inc = pre + cnt;
        const bool found = (pre < R && R <= inc);
        unsigned pk = 0;
        if (found) {
            int c = pre, bb = -1, cb = 0; unsigned hbv = 0;
#pragma unroll
            for (int j = 0; j < 8; ++j) {
                if (bb < 0) {
                    if (c + (int)h[j] >= R) { bb = lane * 8 + j; hbv = h[j]; cb = c; }
                    else c += (int)h[j];
                }
            }
            pk = (unsigned)bb | ((unsigned)cb << 9) | (hbv << 16);
        }
        const unsigned long long fm = __ballot(found);
        const int srcl = (int)__ffsll(fm) - 1;
        pk = (unsigned)__builtin_amdgcn_readlane((int)pk, srcl);
        const int bbin = (int)(pk & 511u);
        const int cb   = (int)((pk >> 9) & 127u);
        const int hb   = (int)(pk >> 16);
        const int need = R - cb;                      // 1..hb
        if (hb == need) {
            bsel = bbin + 1; R = 0;                   // take all bins <= bbin
        } else {
            bsel = bbin; R = need;                    // boundary handled by extraction
            // nam sweep: boundary-bin members
            unsigned nam = 0u;
#pragma unroll
            for (int i = 0; i < 16; ++i) {
                if (bits[i] <= tmax) {
                    const int b = (int)((bits[i] - base) >> shift);
                    if (b == bbin) nam |= 1u << i;
                }
            }
            // value-group extraction over nam (exact; terminates: >=1 group/iter)
#pragma unroll 1
            while (R > 0) {
                unsigned lmin = 0xFFFFFFFFu;
#pragma unroll
                for (int i = 0; i < 16; ++i)
                    if ((nam >> i) & 1) lmin = min(lmin, bits[i]);
                unsigned vmin = lmin;
#pragma unroll
                for (int off = 1; off < 64; off <<= 1)
                    vmin = min(vmin, (unsigned)__shfl_xor((int)vmin, off));
                unsigned eq = 0u;
#pragma unroll
                for (int i = 0; i < 16; ++i)
                    if (((nam >> i) & 1) && bits[i] == vmin) eq |= 1u << i;
                const int ec = __popc(eq);
                int tot = 0;
#pragma unroll
                for (int b = 0; b < 5; ++b) {
                    const unsigned long long mk = __ballot((ec >> b) & 1);
                    tot += (int)__popcll(mk) << b;
                }
                if (tot <= R) {
                    sm |= eq; nam &= ~eq; R -= tot;
                } else {
                    // O(1) fill: R smallest-q among eq; q = 4*lane + j + 256*c
#pragma unroll
                    for (int c = 0; c < 4; ++c) {
                        if (R > 0) {
                            const unsigned nib = (eq >> (4 * c)) & 0xFu;
                            const int cn = __popc(nib);
                            int prel = 0, totc = 0;
#pragma unroll
                            for (int b = 0; b < 3; ++b) {
                                const unsigned long long mk = __ballot((cn >> b) & 1);
                                prel += (int)__popcll(mk & lmask) << b;
                                totc += (int)__popcll(mk) << b;
                            }
                            int take = R - prel;
                            take = take < 0 ? 0 : (take > cn ? cn : take);
#pragma unroll
                            for (int j = 0; j < 4; ++j) {
                                if (((nib >> j) & 1) && take > 0) { sm |= 1u << (4 * c + j); --take; }
                            }
                            R -= totc < R ? totc : R;
                        }
                    }
                    R = 0;
                }
            }
        }
    } else {
        // all actives share one value (or span 0): R smallest-q among actives
        unsigned nam = 0u;
#pragma unroll
        for (int i = 0; i < 16; ++i) nam |= (bits[i] <= tmax) ? (1u << i) : 0u;
#pragma unroll
        for (int c = 0; c < 4; ++c) {
            if (R > 0) {
                const unsigned nib = (nam >> (4 * c)) & 0xFu;
                const int cn = __popc(nib);
                int prel = 0, totc = 0;
#pragma unroll
                for (int b = 0; b < 3; ++b) {
                    const unsigned long long mk = __ballot((cn >> b) & 1);
                    prel += (int)__popcll(mk & lmask) << b;
                    totc += (int)__popcll(mk) << b;
                }
                int take = R - prel;
                take = take < 0 ? 0 : (take > cn ? cn : take);
#pragma unroll
                for (int j = 0; j < 4; ++j) {
                    if (((nib >> j) & 1) && take > 0) { sm |= 1u << (4 * c + j); --take; }
                }
                R -= totc < R ? totc : R;
            }
        }
        R = 0;
    }

    // sweep D: fused classify+emit (predicate inline, 1 ballot/slot)
    int* out = nbr + (size_t)(cloud * PPTS + pl0 + r) * KNB;
    int slotbase = 0;
#pragma unroll
    for (int i = 0; i < 16; ++i) {
        bool sel = (sm >> i) & 1;
        if (bits[i] <= tmax) {
            const int b = (int)((bits[i] - base) >> shift);
            sel = sel || (b < bsel);
        }
        const unsigned long long mb = __ballot(sel);
        if (sel) {
            const int slot = slotbase + (int)__popcll(mb & lmask);
            if (slot < KNB) out[slot] = cloud * PPTS + 4 * lane + (i & 3) + 256 * (i >> 2);
        }
        slotbase += (int)__popcll(mb);
    }
    if (lane == 0)
        for (int s = slotbase; s < KNB; ++s) out[s] = cloud * PPTS + pl0 + r;
}

// ---------------------------------------------------------------------------
// Combine (float4 + XCD swizzle): x_out = relu(A + max_k Bm[nbr])
// ---------------------------------------------------------------------------
template<int FO>
__global__ __launch_bounds__(256) void combine_kernel(const float* __restrict__ A,
                                                      const float* __restrict__ Bm,
                                                      const int* __restrict__ nbr,
                                                      float* __restrict__ xout) {
    constexpr int FO4 = FO / 4;
    const int bid = (int)((blockIdx.x & 7) * (gridDim.x >> 3) + (blockIdx.x >> 3));
    const int idx = bid * 256 + threadIdx.x;
    const int n  = idx / FO4;
    const int o4 = idx % FO4;
    const int* nb = nbr + (size_t)n * KNB;
    const float4* B4 = reinterpret_cast<const float4*>(Bm);
    float4 mx = make_float4(-FLT_MAX, -FLT_MAX, -FLT_MAX, -FLT_MAX);
#pragma unroll 8
    for (int k = 0; k < KNB; ++k) {
        const float4 v = B4[(size_t)nb[k] * FO4 + o4];
        mx.x = fmaxf(mx.x, v.x); mx.y = fmaxf(mx.y, v.y);
        mx.z = fmaxf(mx.z, v.z); mx.w = fmaxf(mx.w, v.w);
    }
    const float4 a = reinterpret_cast<const float4*>(A)[idx];
    float4 rr;
    rr.x = fmaxf(a.x + mx.x, 0.f);
    rr.y = fmaxf(a.y + mx.y, 0.f);
    rr.z = fmaxf(a.z + mx.z, 0.f);
    rr.w = fmaxf(a.w + mx.w, 0.f);
    reinterpret_cast<float4*>(xout)[idx] = rr;
}

// ---------------------------------------------------------------------------
// Classifier GEMM (R15-proven): logits = X @ Wc + bc, 320 threads/block.
// ---------------------------------------------------------------------------
__global__ __launch_bounds__(320) void cls_gemm_kernel(const float* __restrict__ x,
                                                       const float* __restrict__ Wc,
                                                       const float* __restrict__ bc,
                                                       float* __restrict__ logits) {
    constexpr int RT = 16;
    __shared__ float xs[RT][256];
    __shared__ float wsm[256][NCLS];
    const int tid = threadIdx.x;
    const int n0  = blockIdx.x * RT;

    const float4* xsrc = reinterpret_cast<const float4*>(x + (size_t)n0 * 256);
    float4* xdst = reinterpret_cast<float4*>(&xs[0][0]);
    for (int i = tid; i < RT * 256 / 4; i += 320) xdst[i] = xsrc[i];
    for (int i = tid; i < 256 * NCLS; i += 320) wsm[i / NCLS][i % NCLS] = Wc[i];
    __syncthreads();

    const int o  = tid % NCLS;
    const int rg = tid / NCLS;
    float acc0 = 0.f, acc1 = 0.f;
#pragma unroll 4
    for (int f4 = 0; f4 < 64; ++f4) {
        float wv0 = wsm[4 * f4 + 0][o];
        float wv1 = wsm[4 * f4 + 1][o];
        float wv2 = wsm[4 * f4 + 2][o];
        float wv3 = wsm[4 * f4 + 3][o];
        const float4 xa = *reinterpret_cast<const float4*>(&xs[rg][4 * f4]);
        const float4 xb = *reinterpret_cast<const float4*>(&xs[rg + 8][4 * f4]);
        acc0 = fmaf(xa.x, wv0, acc0); acc0 = fmaf(xa.y, wv1, acc0);
        acc0 = fmaf(xa.z, wv2, acc0); acc0 = fmaf(xa.w, wv3, acc0);
        acc1 = fmaf(xb.x, wv0, acc1); acc1 = fmaf(xb.y, wv1, acc1);
        acc1 = fmaf(xb.z, wv2, acc1); acc1 = fmaf(xb.w, wv3, acc1);
    }
    const float bo = bc[o];
    logits[(size_t)(n0 + rg) * NCLS + o]     = acc0 + bo;
    logits[(size_t)(n0 + rg + 8) * NCLS + o] = acc1 + bo;
}

// ---------------------------------------------------------------------------
// Softmax + per-row loss
// ---------------------------------------------------------------------------
__global__ __launch_bounds__(256) void softmax_loss_kernel(const float* __restrict__ logits,
                                                           const int* __restrict__ target,
                                                           float* __restrict__ probs,
                                                           float* __restrict__ lossbuf) {
    const int tid = threadIdx.x;
    const int lane = tid & 63;
    const int n = blockIdx.x * 4 + (tid >> 6);
    float logit = -FLT_MAX;
    if (lane < NCLS) logit = logits[(size_t)n * NCLS + lane];
    float m = logit;
#pragma unroll
    for (int off = 32; off; off >>= 1) m = fmaxf(m, __shfl_xor(m, off));
    const float e = (lane < NCLS) ? __expf(logit - m) : 0.f;
    float s = e;
#pragma unroll
    for (int off = 32; off; off >>= 1) s += __shfl_xor(s, off);
    if (lane < NCLS) probs[(size_t)n * NCLS + lane] = e / s;
    const float lt = __shfl(logit, target[n]);
    if (lane == 0) lossbuf[n] = logf(s) - (lt - m);
}

__global__ __launch_bounds__(256) void loss_reduce_kernel(const float* __restrict__ lossbuf,
                                                          float* __restrict__ out) {
    __shared__ float s[256];
    float acc = 0.f;
    for (int i = threadIdx.x; i < NPTS; i += 256) acc += lossbuf[i];
    s[threadIdx.x] = acc;
    __syncthreads();
    for (int off = 128; off; off >>= 1) {
        if (threadIdx.x < off) s[threadIdx.x] += s[threadIdx.x + off];
        __syncthreads();
    }
    if (threadIdx.x == 0) out[0] = s[0] / (float)NPTS;
}

extern "C" void kernel_launch(void* const* d_in, const int* in_sizes, int n_in,
                              void* d_out, int out_size, void* d_ws, size_t ws_size,
                              hipStream_t stream) {
    (void)in_sizes; (void)n_in; (void)out_size; (void)ws_size;
    const float* x_in   = (const float*)d_in[0];
    const int*   target = (const int*)d_in[2];
    const float* W1 = (const float*)d_in[3];
    const float* b1 = (const float*)d_in[4];
    const float* W2 = (const float*)d_in[5];
    const float* b2 = (const float*)d_in[6];
    const float* W3 = (const float*)d_in[7];
    const float* b3 = (const float*)d_in[8];
    const float* Wc = (const float*)d_in[9];
    const float* bc = (const float*)d_in[10];

    // proven-safe window [0, 50MB+64KB) (R18-R20 layout):
    //   X [0,8M live during kNN) | xT [8,16M) | A [16,32M) | Bm [32,48M)
    //   nbr [48,50M) | qn==lossbuf [50M,+64K) | logits alias dead-A
    char* ws = (char*)d_ws;
    float* X       = (float*)(ws);
    float* xT      = (float*)(ws + (size_t)8  * 1024 * 1024);
    float* A       = (float*)(ws + (size_t)16 * 1024 * 1024);
    float* Bm      = (float*)(ws + (size_t)32 * 1024 * 1024);
    int*   nbr     = (int*)  (ws + (size_t)48 * 1024 * 1024);
    float* lossbuf = (float*)(ws + (size_t)50 * 1024 * 1024);
    float* qn      = lossbuf;
    float* logits  = (float*)(ws + (size_t)16 * 1024 * 1024);

    float* outF  = (float*)d_out;
    float* probs = outF + 1;

    // ---- layer 1 (3 -> 64) ----
    xpose_kernel<3><<<NPTS / 256, 256, 0, stream>>>(x_in, xT, qn);
    knn_edge_kernel<3, 64><<<KNNBLK + EDGEBLK, 256, 0, stream>>>(x_in, xT, qn, nbr, W1, b1, A, Bm);
    combine_kernel<64><<<NPTS * 16 / 256, 256, 0, stream>>>(A, Bm, nbr, X);

    // ---- layer 2 (64 -> 128) ----
    xpose_kernel<64><<<NPTS / 256, 256, 0, stream>>>(X, xT, qn);
    knn_edge_kernel<64, 128><<<KNNBLK + EDGEBLK, 256, 0, stream>>>(X, xT, qn, nbr, W2, b2, A, Bm);
    combine_kernel<128><<<NPTS * 32 / 256, 256, 0, stream>>>(A, Bm, nbr, X);

    // ---- layer 3 (128 -> 256) ----
    xpose_kernel<128><<<NPTS / 256, 256, 0, stream>>>(X, xT, qn);
    knn_edge_kernel<128, 256><<<KNNBLK + EDGEBLK, 256, 0, stream>>>(X, xT, qn, nbr, W3, b3, A, Bm);
    combine_kernel<256><<<NPTS * 64 / 256, 256, 0, stream>>>(A, Bm, nbr, X);

    // ---- classifier + loss ----
    cls_gemm_kernel<<<NPTS / 16, 320, 0, stream>>>(X, Wc, bc, logits);
    softmax_loss_kernel<<<NPTS / 4, 256, 0, stream>>>(logits, target, probs, lossbuf);
    loss_reduce_kernel<<<1, 256, 0, stream>>>(lossbuf, outF);
}

// Round 22
// 323.312 us; speedup vs baseline: 1.1892x; 1.0180x over previous
//
#include <hip/hip_runtime.h>
#include <float.h>
#include <math.h>

#define BCLOUDS 16
#define PPTS    1024
#define NPTS    (BCLOUDS * PPTS)
#define KNB     32
#define NCLS    40
#define RPB     4                  // rows per knn block (= waves per block)
#define KNNBLK  (NPTS / RPB)       // 4096 knn blocks
#define EDGEBLK (NPTS / 16)        // 1024 edge blocks
#define NBINS   512                // bins (9 bits), single pass
#define HWORDS  (NBINS / 2)        // u16-packed words
#define WPADW   (HWORDS + HWORDS / 16)
#define SELFM   0xFFFFFFFFu        // self marker: above every real distance bit pattern

__device__ __forceinline__ int widx(int w) { return w + (w >> 4); }
__device__ __forceinline__ int slotq(int lane, int i) { return 4 * lane + (i & 3) + 256 * (i >> 2); }

// ---------------------------------------------------------------------------
// Transpose + norms: xT[cloud][f][p] = x[cloud*1024+p][f]; qn[p] = |x_p|^2
// ---------------------------------------------------------------------------
template<int F>
__global__ __launch_bounds__(256) void xpose_kernel(const float* __restrict__ x,
                                                    float* __restrict__ xT,
                                                    float* __restrict__ qn) {
    const int p = blockIdx.x * 256 + threadIdx.x;
    const int cloud = p >> 10, pl = p & 1023;
    const float* xr = x + (size_t)p * F;
    float* xTc = xT + (size_t)cloud * F * PPTS;
    float s = 0.f;
    for (int f = 0; f < F; ++f) {
        const float v = xr[f];
        s = fmaf(v, v, s);
        xTc[(size_t)f * PPTS + pl] = v;
    }
    qn[p] = s;
}

// ---------------------------------------------------------------------------
// FUSED kNN + edge-GEMM. Selection = ACTIVE-COMPACTED single-pass radix:
// after the irreducible 16-wide min-chain + T-reduce, only ~1.5 active
// slots/lane (bits <= T; wave total ~96) are processed: first two held
// statically (i0/v0, i1/v1 — no register arrays), overflow actives walked
// via __ffs with LDS re-reads by computed address. Emit = unordered per-row
// LDS slot counter (R5-proven; membership exact, order irrelevant for max).
// Exactness: T = max of lower-32 lane minima >= 32nd smallest; boundary &
// degenerate ties resolved by (value,q)-key / ascending-q iterative picks
// (q globally unique -> unique winner) matching lax.top_k.
// ---------------------------------------------------------------------------
template<int F, int FO>
__global__ __launch_bounds__(256, 2) void knn_edge_kernel(const float* __restrict__ x,
                                                          const float* __restrict__ xT,
                                                          const float* __restrict__ qn,
                                                          int* __restrict__ nbr,
                                                          const float* __restrict__ W,
                                                          const float* __restrict__ bias,
                                                          float* __restrict__ A,
                                                          float* __restrict__ Bm) {
    __shared__ unsigned dmat[RPB][PPTS];     // 16 KB
    __shared__ float    xp[RPB][F];
    __shared__ float    rn[RPB];
    __shared__ unsigned histw[RPB][WPADW];   // 4.4 KB
    __shared__ unsigned slotctr[RPB];
    __shared__ float    xs[16][F];           // edge path

    const int tid = threadIdx.x;

    if (blockIdx.x >= KNNBLK) {
        // ================= edge GEMM path (verbatim) =================
        constexpr int RT  = 16;
        constexpr int RS  = 256 / FO;
        constexpr int RPT = RT / RS;
        const int n0 = (int)(blockIdx.x - KNNBLK) * RT;
        for (int i = tid; i < RT * F; i += 256)
            xs[i / F][i % F] = x[(size_t)n0 * F + i];
        __syncthreads();

        const int o  = tid % FO;
        const int r0 = tid / FO;
        float accA[RPT], accB[RPT];
#pragma unroll
        for (int i = 0; i < RPT; ++i) { accA[i] = 0.f; accB[i] = 0.f; }

        for (int f = 0; f < F; ++f) {
            const float wt = W[(size_t)f * FO + o];
            const float wb = W[(size_t)(F + f) * FO + o];
            const float wd = wt - wb;
#pragma unroll
            for (int i = 0; i < RPT; ++i) {
                const float xv = xs[r0 + i * RS][f];
                accA[i] = fmaf(xv, wd, accA[i]);
                accB[i] = fmaf(xv, wb, accB[i]);
            }
        }
        const float bo = bias[o];
#pragma unroll
        for (int i = 0; i < RPT; ++i) {
            const size_t row = (size_t)(n0 + r0 + i * RS);
            A[row * FO + o]  = accA[i] + bo;
            Bm[row * FO + o] = accB[i];
        }
        return;
    }

    // ==================== kNN path ====================
    const int lane  = tid & 63;
    const int wave  = tid >> 6;            // 0..3
    const int bid   = blockIdx.x;
    const int cloud = (bid & 7) + 8 * (bid >> 11);
    const int pl0   = ((bid >> 3) & 255) * RPB;

    const float* xc = x + (size_t)cloud * PPTS * F;
    for (int i = tid; i < RPB * F; i += 256)
        xp[i / F][i % F] = xc[(size_t)(pl0 + i / F) * F + (i % F)];
    __syncthreads();
    if (tid < RPB) {
        float s = 0.f;
        for (int f = 0; f < F; ++f) { const float v = xp[tid][f]; s = fmaf(v, v, s); }
        rn[tid] = s;
    }
    __syncthreads();

    const float* xTc = xT + (size_t)cloud * F * PPTS;
    const float4 qv = *reinterpret_cast<const float4*>(&qn[cloud * PPTS + 4 * tid]);

    float acc[RPB][4];
#pragma unroll
    for (int r = 0; r < RPB; ++r)
#pragma unroll
        for (int c = 0; c < 4; ++c) acc[r][c] = 0.f;

    if constexpr (F % 4 == 0) {
#pragma unroll 2
        for (int f4 = 0; f4 < F / 4; ++f4) {
            float4 vf[4];
#pragma unroll
            for (int j = 0; j < 4; ++j)
                vf[j] = *reinterpret_cast<const float4*>(&xTc[(size_t)(4 * f4 + j) * PPTS + 4 * tid]);
            float4 xr[RPB];
#pragma unroll
            for (int r = 0; r < RPB; ++r) xr[r] = *reinterpret_cast<const float4*>(&xp[r][4 * f4]);
#pragma unroll
            for (int r = 0; r < RPB; ++r) {
                acc[r][0] = fmaf(vf[0].x, xr[r].x, acc[r][0]);
                acc[r][1] = fmaf(vf[0].y, xr[r].x, acc[r][1]);
                acc[r][2] = fmaf(vf[0].z, xr[r].x, acc[r][2]);
                acc[r][3] = fmaf(vf[0].w, xr[r].x, acc[r][3]);
                acc[r][0] = fmaf(vf[1].x, xr[r].y, acc[r][0]);
                acc[r][1] = fmaf(vf[1].y, xr[r].y, acc[r][1]);
                acc[r][2] = fmaf(vf[1].z, xr[r].y, acc[r][2]);
                acc[r][3] = fmaf(vf[1].w, xr[r].y, acc[r][3]);
                acc[r][0] = fmaf(vf[2].x, xr[r].z, acc[r][0]);
                acc[r][1] = fmaf(vf[2].y, xr[r].z, acc[r][1]);
                acc[r][2] = fmaf(vf[2].z, xr[r].z, acc[r][2]);
                acc[r][3] = fmaf(vf[2].w, xr[r].z, acc[r][3]);
                acc[r][0] = fmaf(vf[3].x, xr[r].w, acc[r][0]);
                acc[r][1] = fmaf(vf[3].y, xr[r].w, acc[r][1]);
                acc[r][2] = fmaf(vf[3].z, xr[r].w, acc[r][2]);
                acc[r][3] = fmaf(vf[3].w, xr[r].w, acc[r][3]);
            }
        }
    } else {
        for (int f = 0; f < F; ++f) {
            const float4 v = *reinterpret_cast<const float4*>(&xTc[(size_t)f * PPTS + 4 * tid]);
#pragma unroll
            for (int r = 0; r < RPB; ++r) {
                const float xv = xp[r][f];
                acc[r][0] = fmaf(v.x, xv, acc[r][0]);
                acc[r][1] = fmaf(v.y, xv, acc[r][1]);
                acc[r][2] = fmaf(v.z, xv, acc[r][2]);
                acc[r][3] = fmaf(v.w, xv, acc[r][3]);
            }
        }
    }
#pragma unroll
    for (int r = 0; r < RPB; ++r) {
        uint4 wv;
        float d2;
        d2 = fmaxf(rn[r] + qv.x - 2.f * acc[r][0], 0.f);
        wv.x = (4 * tid + 0 == pl0 + r) ? SELFM : __float_as_uint(d2);
        d2 = fmaxf(rn[r] + qv.y - 2.f * acc[r][1], 0.f);
        wv.y = (4 * tid + 1 == pl0 + r) ? SELFM : __float_as_uint(d2);
        d2 = fmaxf(rn[r] + qv.z - 2.f * acc[r][2], 0.f);
        wv.z = (4 * tid + 2 == pl0 + r) ? SELFM : __float_as_uint(d2);
        d2 = fmaxf(rn[r] + qv.w - 2.f * acc[r][3], 0.f);
        wv.w = (4 * tid + 3 == pl0 + r) ? SELFM : __float_as_uint(d2);
        *reinterpret_cast<uint4*>(&dmat[r][4 * tid]) = wv;
    }
    __syncthreads();

    // ---- selection: wave w row w; slot i = 4c+j <-> q = 4*lane + j + 256*c
    unsigned* hw = histw[wave];
    const int r = wave;
    const unsigned long long lmask = (1ull << lane) - 1ull;
    unsigned bits[16];
#pragma unroll
    for (int c = 0; c < 4; ++c) {
        const uint4 bv = *reinterpret_cast<const uint4*>(&dmat[r][4 * lane + 256 * c]);
        bits[4 * c + 0] = bv.x; bits[4 * c + 1] = bv.y;
        bits[4 * c + 2] = bv.z; bits[4 * c + 3] = bv.w;
    }

    // phase 1: min chain + reduces (irreducible 16-wide part)
    unsigned m = bits[0];
#pragma unroll
    for (int i = 1; i < 16; ++i) m = min(m, bits[i]);
    unsigned gmin = m;
    unsigned tmax = (lane < 32) ? m : 0u;
#pragma unroll
    for (int off = 1; off < 64; off <<= 1) {
        gmin = min(gmin, (unsigned)__shfl_xor((int)gmin, off));
        tmax = max(tmax, (unsigned)__shfl_xor((int)tmax, off));
    }

    // compaction: active mask + first two actives held statically
    unsigned act = 0u, v0 = 0u, v1 = 0u;
    int i0 = -1, i1 = -1;
#pragma unroll
    for (int i = 0; i < 16; ++i) {
        if (bits[i] <= tmax) {
            act |= 1u << i;
            if (i0 < 0)      { i0 = i; v0 = bits[i]; }
            else if (i1 < 0) { i1 = i; v1 = bits[i]; }
        }
    }
    unsigned ov = act & (act - 1); ov &= (ov - 1);   // actives beyond first two

    unsigned selm = 0u;        // extraction-selected slots (per-lane 16-bit)
    int bsel = -1;             // emit: actives with bin < bsel selected
    int R = KNB;
    const unsigned base = gmin;
    int shift = 0;
    const bool have = tmax > gmin;
    int b0 = -1, b1 = -1;

    if (have) {
        const unsigned span = tmax - gmin;
        const int lg = 31 - __clz(span);
        shift = lg > 8 ? lg - 8 : 0;       // actives -> bins [0,511]

        // zero u16-packed 512-bin hist
#pragma unroll
        for (int j = 0; j < 5; ++j) { const int k2 = lane + j * 64; if (k2 < WPADW) hw[k2] = 0u; }
        // bin compacted actives only
        if (i0 >= 0) { b0 = (int)((v0 - base) >> shift); atomicAdd(&hw[widx(b0 >> 1)], 1u << ((b0 & 1) << 4)); }
        if (i1 >= 0) { b1 = (int)((v1 - base) >> shift); atomicAdd(&hw[widx(b1 >> 1)], 1u << ((b1 & 1) << 4)); }
        {
            unsigned t = ov;
            while (t) {
                const int i = __ffs(t) - 1; t &= t - 1;
                const unsigned v = dmat[r][slotq(lane, i)];
                const int b = (int)((v - base) >> shift);
                atomicAdd(&hw[widx(b >> 1)], 1u << ((b & 1) << 4));
            }
        }
        // scan: 8 bins/lane, ballot prefix (SALU)
        unsigned h[8];
        int cnt = 0;
#pragma unroll
        for (int j = 0; j < 4; ++j) {
            const unsigned w = hw[widx(4 * lane + j)];
            h[2 * j]     = w & 0xFFFFu;
            h[2 * j + 1] = w >> 16;
            cnt += (int)(h[2 * j] + h[2 * j + 1]);
        }
        int pre = 0;
#pragma unroll
        for (int b = 0; b < 11; ++b) {
            const unsigned long long mk = __ballot((cnt >> b) & 1);
            pre += (int)__popcll(mk & lmask) << b;
        }
        const int inc = pre + cnt;
        const bool found = (pre < R && R <= inc);
        unsigned pk = 0;
        if (found) {
            int c = pre, bb = -1, cb = 0; unsigned hbv = 0;
#pragma unroll
            for (int j = 0; j < 8; ++j) {
                if (bb < 0) {
                    if (c + (int)h[j] >= R) { bb = lane * 8 + j; hbv = h[j]; cb = c; }
                    else c += (int)h[j];
                }
            }
            pk = (unsigned)bb | ((unsigned)cb << 9) | (hbv << 16);
        }
        const unsigned long long fm = __ballot(found);
        const int srcl = (int)__ffsll(fm) - 1;
        pk = (unsigned)__builtin_amdgcn_readlane((int)pk, srcl);
        const int bbin = (int)(pk & 511u);
        const int cb   = (int)((pk >> 9) & 127u);
        const int hb   = (int)(pk >> 16);
        const int need = R - cb;                      // 1..hb
        if (hb == need) {
            bsel = bbin + 1; R = 0;                   // take all bins <= bbin
        } else {
            bsel = bbin; R = need;
            // boundary mask (compacted)
            unsigned bm = 0u;
            if (b0 == bbin) bm |= 1u << i0;
            if (b1 == bbin) bm |= 1u << i1;
            {
                unsigned t = ov;
                while (t) {
                    const int i = __ffs(t) - 1; t &= t - 1;
                    const unsigned v = dmat[r][slotq(lane, i)];
                    if ((int)((v - base) >> shift) == bbin) bm |= 1u << i;
                }
            }
            // iterative exact extraction by (value, q) key (q unique -> unique winner)
#pragma unroll 1
            while (R > 0) {
                unsigned long long best = ~0ull;
                unsigned t = bm;
                while (t) {
                    const int i = __ffs(t) - 1; t &= t - 1;
                    const int q = slotq(lane, i);
                    const unsigned v = dmat[r][q];
                    const unsigned long long key = ((unsigned long long)v << 12) | (unsigned)q;
                    best = best < key ? best : key;
                }
                unsigned long long gbest = best;
#pragma unroll
                for (int off = 1; off < 64; off <<= 1) {
                    const unsigned long long o = __shfl_xor(gbest, off);
                    gbest = o < gbest ? o : gbest;
                }
                const int qw = (int)(gbest & 0xFFFu);
                if (((qw & 255) >> 2) == lane) {
                    const int iw = ((qw >> 8) << 2) | (qw & 3);
                    selm |= 1u << iw;
                    bm &= ~(1u << iw);
                }
                --R;
            }
        }
    } else {
        // all actives equal -> R smallest-q (q monotone in slot index i per lane)
        unsigned bm = act;
#pragma unroll 1
        while (R > 0) {
            const int il = __ffs(bm) - 1;
            const int ql = (bm != 0u) ? slotq(lane, il) : 4096;
            int gq = ql;
#pragma unroll
            for (int off = 1; off < 64; off <<= 1) gq = min(gq, __shfl_xor(gq, off));
            if (ql == gq && bm != 0u) { selm |= 1u << il; bm &= ~(1u << il); }
            --R;
        }
    }

    // emit: unordered per-row atomic slot (R5-proven; order irrelevant for max)
    if (lane == 0) slotctr[wave] = 0u;     // same-wave DS order: init before atomics
    int* out = nbr + (size_t)(cloud * PPTS + pl0 + r) * KNB;
    if (i0 >= 0) {
        const bool sel = ((selm >> i0) & 1) || (b0 >= 0 && b0 < bsel);
        if (sel) {
            const unsigned slot = atomicAdd(&slotctr[wave], 1u);
            if (slot < KNB) out[slot] = cloud * PPTS + slotq(lane, i0);
        }
    }
    if (i1 >= 0) {
        const bool sel = ((selm >> i1) & 1) || (b1 >= 0 && b1 < bsel);
        if (sel) {
            const unsigned slot = atomicAdd(&slotctr[wave], 1u);
            if (slot < KNB) out[slot] = cloud * PPTS + slotq(lane, i1);
        }
    }
    {
        unsigned t = ov;
        while (t) {
            const int i = __ffs(t) - 1; t &= t - 1;
            const int q = slotq(lane, i);
            bool sel = (selm >> i) & 1;
            if (!sel && bsel > 0) {
                const unsigned v = dmat[r][q];
                sel = ((int)((v - base) >> shift) < bsel);
            }
            if (sel) {
                const unsigned slot = atomicAdd(&slotctr[wave], 1u);
                if (slot < KNB) out[slot] = cloud * PPTS + q;
            }
        }
    }
    const unsigned tot = slotctr[wave];    // same-wave ordering: sees own atomics
    if (lane == 0)
        for (unsigned s = tot; s < KNB; ++s) out[s] = cloud * PPTS + pl0 + r;
}

// ---------------------------------------------------------------------------
// Combine (float4 + XCD swizzle): x_out = relu(A + max_k Bm[nbr])
// ---------------------------------------------------------------------------
template<int FO>
__global__ __launch_bounds__(256) void combine_kernel(const float* __restrict__ A,
                                                      const float* __restrict__ Bm,
                                                      const int* __restrict__ nbr,
                                                      float* __restrict__ xout) {
    constexpr int FO4 = FO / 4;
    const int bid = (int)((blockIdx.x & 7) * (gridDim.x >> 3) + (blockIdx.x >> 3));
    const int idx = bid * 256 + threadIdx.x;
    const int n  = idx / FO4;
    const int o4 = idx % FO4;
    const int* nb = nbr + (size_t)n * KNB;
    const float4* B4 = reinterpret_cast<const float4*>(Bm);
    float4 mx = make_float4(-FLT_MAX, -FLT_MAX, -FLT_MAX, -FLT_MAX);
#pragma unroll 8
    for (int k = 0; k < KNB; ++k) {
        const float4 v = B4[(size_t)nb[k] * FO4 + o4];
        mx.x = fmaxf(mx.x, v.x); mx.y = fmaxf(mx.y, v.y);
        mx.z = fmaxf(mx.z, v.z); mx.w = fmaxf(mx.w, v.w);
    }
    const float4 a = reinterpret_cast<const float4*>(A)[idx];
    float4 rr;
    rr.x = fmaxf(a.x + mx.x, 0.f);
    rr.y = fmaxf(a.y + mx.y, 0.f);
    rr.z = fmaxf(a.z + mx.z, 0.f);
    rr.w = fmaxf(a.w + mx.w, 0.f);
    reinterpret_cast<float4*>(xout)[idx] = rr;
}

// ---------------------------------------------------------------------------
// Classifier GEMM (R15-proven): logits = X @ Wc + bc, 320 threads/block.
// ---------------------------------------------------------------------------
__global__ __launch_bounds__(320) void cls_gemm_kernel(const float* __restrict__ x,
                                                       const float* __restrict__ Wc,
                                                       const float* __restrict__ bc,
                                                       float* __restrict__ logits) {
    constexpr int RT = 16;
    __shared__ float xs[RT][256];
    __shared__ float wsm[256][NCLS];
    const int tid = threadIdx.x;
    const int n0  = blockIdx.x * RT;

    const float4* xsrc = reinterpret_cast<const float4*>(x + (size_t)n0 * 256);
    float4* xdst = reinterpret_cast<float4*>(&xs[0][0]);
    for (int i = tid; i < RT * 256 / 4; i += 320) xdst[i] = xsrc[i];
    for (int i = tid; i < 256 * NCLS; i += 320) wsm[i / NCLS][i % NCLS] = Wc[i];
    __syncthreads();

    const int o  = tid % NCLS;
    const int rg = tid / NCLS;
    float acc0 = 0.f, acc1 = 0.f;
#pragma unroll 4
    for (int f4 = 0; f4 < 64; ++f4) {
        float wv0 = wsm[4 * f4 + 0][o];
        float wv1 = wsm[4 * f4 + 1][o];
        float wv2 = wsm[4 * f4 + 2][o];
        float wv3 = wsm[4 * f4 + 3][o];
        const float4 xa = *reinterpret_cast<const float4*>(&xs[rg][4 * f4]);
        const float4 xb = *reinterpret_cast<const float4*>(&xs[rg + 8][4 * f4]);
        acc0 = fmaf(xa.x, wv0, acc0); acc0 = fmaf(xa.y, wv1, acc0);
        acc0 = fmaf(xa.z, wv2, acc0); acc0 = fmaf(xa.w, wv3, acc0);
        acc1 = fmaf(xb.x, wv0, acc1); acc1 = fmaf(xb.y, wv1, acc1);
        acc1 = fmaf(xb.z, wv2, acc1); acc1 = fmaf(xb.w, wv3, acc1);
    }
    const float bo = bc[o];
    logits[(size_t)(n0 + rg) * NCLS + o]     = acc0 + bo;
    logits[(size_t)(n0 + rg + 8) * NCLS + o] = acc1 + bo;
}

// ---------------------------------------------------------------------------
// Softmax + per-row loss
// ---------------------------------------------------------------------------
__global__ __launch_bounds__(256) void softmax_loss_kernel(const float* __restrict__ logits,
                                                           const int* __restrict__ target,
                                                           float* __restrict__ probs,
                                                           float* __restrict__ lossbuf) {
    const int tid = threadIdx.x;
    const int lane = tid & 63;
    const int n = blockIdx.x * 4 + (tid >> 6);
    float logit = -FLT_MAX;
    if (lane < NCLS) logit = logits[(size_t)n * NCLS + lane];
    float m = logit;
#pragma unroll
    for (int off = 32; off; off >>= 1) m = fmaxf(m, __shfl_xor(m, off));
    const float e = (lane < NCLS) ? __expf(logit - m) : 0.f;
    float s = e;
#pragma unroll
    for (int off = 32; off; off >>= 1) s += __shfl_xor(s, off);
    if (lane < NCLS) probs[(size_t)n * NCLS + lane] = e / s;
    const float lt = __shfl(logit, target[n]);
    if (lane == 0) lossbuf[n] = logf(s) - (lt - m);
}

__global__ __launch_bounds__(256) void loss_reduce_kernel(const float* __restrict__ lossbuf,
                                                          float* __restrict__ out) {
    __shared__ float s[256];
    float acc = 0.f;
    for (int i = threadIdx.x; i < NPTS; i += 256) acc += lossbuf[i];
    s[threadIdx.x] = acc;
    __syncthreads();
    for (int off = 128; off; off >>= 1) {
        if (threadIdx.x < off) s[threadIdx.x] += s[threadIdx.x + off];
        __syncthreads();
    }
    if (threadIdx.x == 0) out[0] = s[0] / (float)NPTS;
}

extern "C" void kernel_launch(void* const* d_in, const int* in_sizes, int n_in,
                              void* d_out, int out_size, void* d_ws, size_t ws_size,
                              hipStream_t stream) {
    (void)in_sizes; (void)n_in; (void)out_size; (void)ws_size;
    const float* x_in   = (const float*)d_in[0];
    const int*   target = (const int*)d_in[2];
    const float* W1 = (const float*)d_in[3];
    const float* b1 = (const float*)d_in[4];
    const float* W2 = (const float*)d_in[5];
    const float* b2 = (const float*)d_in[6];
    const float* W3 = (const float*)d_in[7];
    const float* b3 = (const float*)d_in[8];
    const float* Wc = (const float*)d_in[9];
    const float* bc = (const float*)d_in[10];

    // proven-safe window [0, 50MB+64KB) (R18-R21 layout):
    //   X [0,8M live during kNN) | xT [8,16M) | A [16,32M) | Bm [32,48M)
    //   nbr [48,50M) | qn==lossbuf [50M,+64K) | logits alias dead-A
    char* ws = (char*)d_ws;
    float* X       = (float*)(ws);
    float* xT      = (float*)(ws + (size_t)8  * 1024 * 1024);
    float* A       = (float*)(ws + (size_t)16 * 1024 * 1024);
    float* Bm      = (float*)(ws + (size_t)32 * 1024 * 1024);
    int*   nbr     = (int*)  (ws + (size_t)48 * 1024 * 1024);
    float* lossbuf = (float*)(ws + (size_t)50 * 1024 * 1024);
    float* qn      = lossbuf;
    float* logits  = (float*)(ws + (size_t)16 * 1024 * 1024);

    float* outF  = (float*)d_out;
    float* probs = outF + 1;

    // ---- layer 1 (3 -> 64) ----
    xpose_kernel<3><<<NPTS / 256, 256, 0, stream>>>(x_in, xT, qn);
    knn_edge_kernel<3, 64><<<KNNBLK + EDGEBLK, 256, 0, stream>>>(x_in, xT, qn, nbr, W1, b1, A, Bm);
    combine_kernel<64><<<NPTS * 16 / 256, 256, 0, stream>>>(A, Bm, nbr, X);

    // ---- layer 2 (64 -> 128) ----
    xpose_kernel<64><<<NPTS / 256, 256, 0, stream>>>(X, xT, qn);
    knn_edge_kernel<64, 128><<<KNNBLK + EDGEBLK, 256, 0, stream>>>(X, xT, qn, nbr, W2, b2, A, Bm);
    combine_kernel<128><<<NPTS * 32 / 256, 256, 0, stream>>>(A, Bm, nbr, X);

    // ---- layer 3 (128 -> 256) ----
    xpose_kernel<128><<<NPTS / 256, 256, 0, stream>>>(X, xT, qn);
    knn_edge_kernel<128, 256><<<KNNBLK + EDGEBLK, 256, 0, stream>>>(X, xT, qn, nbr, W3, b3, A, Bm);
    combine_kernel<256><<<NPTS * 64 / 256, 256, 0, stream>>>(A, Bm, nbr, X);

    // ---- classifier + loss ----
    cls_gemm_kernel<<<NPTS / 16, 320, 0, stream>>>(X, Wc, bc, logits);
    softmax_loss_kernel<<<NPTS / 4, 256, 0, stream>>>(logits, target, probs, lossbuf);
    loss_reduce_kernel<<<1, 256, 0, stream>>>(lossbuf, outF);
}